// Round 2
// baseline (324.606 us; speedup 1.0000x reference)
//
#include <hip/hip_runtime.h>
#include <hip/hip_bf16.h>
#include <stdint.h>

#define DM  1024
#define SEQ 2048
#define NB  2
#define NH  16
#define DKH 64

typedef unsigned short u16;
typedef __attribute__((ext_vector_type(8))) short short8;
typedef __attribute__((ext_vector_type(4))) float f32x4;

#define MFMA(a,b,c) __builtin_amdgcn_mfma_f32_16x16x32_bf16((a),(b),(c),0,0,0)

__device__ __forceinline__ void async_g2l16(const void* g, void* l) {
  __builtin_amdgcn_global_load_lds(
      (const __attribute__((address_space(1))) uint32_t*)g,
      (__attribute__((address_space(3))) uint32_t*)l, 16, 0, 0);
}

__device__ __forceinline__ u16 f2bf(float f) {
  uint32_t u = __builtin_bit_cast(uint32_t, f);
  u += 0x7fffu + ((u >> 16) & 1u);
  return (u16)(u >> 16);
}

// ---------------------------------------------------------------------------
// f32 -> bf16 convert for q/k/v (grid.z selects tensor). 8 elems/thread.
// ---------------------------------------------------------------------------
__global__ __launch_bounds__(256) void conv3(
    const float* __restrict__ a0, const float* __restrict__ a1,
    const float* __restrict__ a2, u16* __restrict__ out) {
  const int z = blockIdx.z;
  const float* A = (z == 0) ? a0 : (z == 1) ? a1 : a2;
  u16* O = out + (size_t)z * NB * SEQ * DM;
  const size_t i = (size_t)blockIdx.x * 256 + threadIdx.x;
  const float4 a = ((const float4*)A)[i * 2];
  const float4 b = ((const float4*)A)[i * 2 + 1];
  u16 v[8] __attribute__((aligned(16)));
  v[0] = f2bf(a.x); v[1] = f2bf(a.y); v[2] = f2bf(a.z); v[3] = f2bf(a.w);
  v[4] = f2bf(b.x); v[5] = f2bf(b.y); v[6] = f2bf(b.z); v[7] = f2bf(b.w);
  *(uint4*)(O + i * 8) = *(uint4*)v;
}

// ---------------------------------------------------------------------------
// Weight transpose + convert: Wt[n][k] = bf16(W[k][n]), 1024x1024 f32 in.
// ---------------------------------------------------------------------------
__global__ __launch_bounds__(256) void transpose4(
    const float* __restrict__ w0, const float* __restrict__ w1,
    const float* __restrict__ w2, const float* __restrict__ w3,
    u16* __restrict__ o0, u16* __restrict__ o1,
    u16* __restrict__ o2, u16* __restrict__ o3) {
  __shared__ u16 tile[64][65];
  const int z = blockIdx.z;
  const float* W = (z == 0) ? w0 : (z == 1) ? w1 : (z == 2) ? w2 : w3;
  u16* O         = (z == 0) ? o0 : (z == 1) ? o1 : (z == 2) ? o2 : o3;
  const int k0 = blockIdx.x * 64, n0 = blockIdx.y * 64;
  const int t = threadIdx.x;
  const int r = t >> 2, cg = (t & 3) * 16;

  const float* src = W + (size_t)(k0 + r) * DM + n0 + cg;
#pragma unroll
  for (int j = 0; j < 4; ++j) {
    const float4 a = ((const float4*)src)[j];
    tile[r][cg + j * 4 + 0] = f2bf(a.x);
    tile[r][cg + j * 4 + 1] = f2bf(a.y);
    tile[r][cg + j * 4 + 2] = f2bf(a.z);
    tile[r][cg + j * 4 + 3] = f2bf(a.w);
  }
  __syncthreads();
  u16 u[16] __attribute__((aligned(16)));
#pragma unroll
  for (int j = 0; j < 16; ++j) u[j] = tile[cg + j][r];
  u16* dst = O + (size_t)(n0 + r) * DM + k0 + cg;
  *(uint4*)&dst[0] = *(uint4*)&u[0];
  *(uint4*)&dst[8] = *(uint4*)&u[8];
}

// ---------------------------------------------------------------------------
// GEMM: C[M][N] = A[M][K] @ Bt[N][K]^T, A/Bt bf16 row-major, f32 accum.
// 128x128 tile, BK=64, 4 waves (2x2), m97-style global_load_lds staging.
// OUT_F32: store f32 (final proj) else bf16.
// ---------------------------------------------------------------------------
template <int OUT_F32>
__device__ __forceinline__ void gemm128_body(
    const u16* __restrict__ A, const u16* __restrict__ Bt, void* __restrict__ Cv,
    int M, int N, int K, int bx, int by) {
  __shared__ u16 As[128 * 64];
  __shared__ u16 Bs[128 * 64];
  const int m0 = by * 128, n0 = bx * 128;
  const int t = threadIdx.x, w = t >> 6, l = t & 63;
  const int wr = w >> 1, wc = w & 1;
  const int frow = l & 15, fk8 = (l >> 4) * 8;
  f32x4 acc[4][4] = {};

  for (int k0 = 0; k0 < K; k0 += 64) {
#pragma unroll
    for (int i = 0; i < 4; ++i) {
      const int base = (i * 4 + w) * 1024;        // LDS byte base (wave-uniform)
      const int e = (base >> 1) + l * 8;          // per-lane element index
      const int row = e >> 6, col = e & 63;
      async_g2l16(A + (size_t)(m0 + row) * K + k0 + col, (char*)As + base);
      async_g2l16(Bt + (size_t)(n0 + row) * K + k0 + col, (char*)Bs + base);
    }
    __syncthreads();
#pragma unroll
    for (int kk = 0; kk < 2; ++kk) {
      short8 af[4], bf[4];
#pragma unroll
      for (int mi = 0; mi < 4; ++mi)
        af[mi] = *(const short8*)&As[(wr * 64 + mi * 16 + frow) * 64 + kk * 32 + fk8];
#pragma unroll
      for (int ni = 0; ni < 4; ++ni)
        bf[ni] = *(const short8*)&Bs[(wc * 64 + ni * 16 + frow) * 64 + kk * 32 + fk8];
#pragma unroll
      for (int mi = 0; mi < 4; ++mi)
#pragma unroll
        for (int ni = 0; ni < 4; ++ni)
          acc[mi][ni] = MFMA(af[mi], bf[ni], acc[mi][ni]);
    }
    __syncthreads();
  }

  const int crb = (l >> 4) * 4;
  for (int mi = 0; mi < 4; ++mi)
    for (int ni = 0; ni < 4; ++ni)
#pragma unroll
      for (int r = 0; r < 4; ++r) {
        const int row = m0 + wr * 64 + mi * 16 + crb + r;
        const int col = n0 + wc * 64 + ni * 16 + frow;
        if (OUT_F32) ((float*)Cv)[(size_t)row * N + col] = acc[mi][ni][r];
        else         ((u16*)Cv)[(size_t)row * N + col] = f2bf(acc[mi][ni][r]);
      }
}

__global__ __launch_bounds__(256) void gemm_qkv(
    const u16* __restrict__ xin, const u16* __restrict__ wt, u16* __restrict__ out) {
  const int z = blockIdx.z;
  gemm128_body<0>(xin + (size_t)z * NB * SEQ * DM, wt + (size_t)z * DM * DM,
                  out + (size_t)z * NB * SEQ * DM,
                  NB * SEQ, DM, DM, blockIdx.x, blockIdx.y);
}

__global__ __launch_bounds__(256) void gemm_out(
    const u16* __restrict__ A, const u16* __restrict__ Bt, float* __restrict__ C) {
  gemm128_body<1>(A, Bt, C, NB * SEQ, DM, DM, blockIdx.x, blockIdx.y);
}

// ---------------------------------------------------------------------------
// Flash attention. Block = 256 thr (4 waves), 64 q-rows per block (16/wave),
// KV tiles of 64. K staged row-major, V staged transposed (Vt[d][kk]).
// Online softmax per q-row via 16-lane shfl_xor reduces. mask: nonzero -> -inf.
// ---------------------------------------------------------------------------
#define LP 72  // padded LDS row stride (keeps 16B alignment, breaks 128B stride)

__global__ __launch_bounds__(256) void attn(
    const u16* __restrict__ Q, const u16* __restrict__ Kmat,
    const u16* __restrict__ V, const int* __restrict__ mask,
    u16* __restrict__ O) {
  __shared__ u16 Ks[64][LP];
  __shared__ u16 Vt[64][LP];
  __shared__ u16 Ps[4][16][LP];
  const int bid = blockIdx.x;
  const int qt = bid & 31;          // 32 q-tiles of 64
  const int h  = (bid >> 5) & 15;
  const int b  = bid >> 9;
  const int t = threadIdx.x, w = t >> 6, l = t & 63;
  const int frow = l & 15, fk8 = (l >> 4) * 8, crb = (l >> 4) * 4;
  const size_t tok0 = (size_t)b * SEQ;
  const int q0 = qt * 64 + w * 16;  // this wave's first q row (within sequence)
  const int hc = h * DKH;

  short8 qf[2];
#pragma unroll
  for (int ks = 0; ks < 2; ++ks)
    qf[ks] = *(const short8*)(Q + (tok0 + q0 + frow) * DM + hc + ks * 32 + fk8);

  f32x4 o[4] = {};
  float m_run[4], l_run[4];
#pragma unroll
  for (int r = 0; r < 4; ++r) { m_run[r] = -1e30f; l_run[r] = 0.f; }

  const int sr = t >> 2;            // staging row 0..63
  const int sc = (t & 3) * 16;      // staging col group

  for (int kv0 = 0; kv0 < SEQ; kv0 += 64) {
    // --- stage K tile and transposed V tile ---
    {
      const u16* ksrc = Kmat + (tok0 + kv0 + sr) * DM + hc + sc;
      uint4 a0 = *(const uint4*)ksrc;
      uint4 a1 = *(const uint4*)(ksrc + 8);
      *(uint4*)&Ks[sr][sc] = a0;
      *(uint4*)&Ks[sr][sc + 8] = a1;
      const u16* vsrc = V + (tok0 + kv0 + sr) * DM + hc + sc;
      u16 vv[16] __attribute__((aligned(16)));
      *(uint4*)&vv[0] = *(const uint4*)vsrc;
      *(uint4*)&vv[8] = *(const uint4*)(vsrc + 8);
#pragma unroll
      for (int j = 0; j < 16; ++j) Vt[sc + j][sr] = vv[j];
    }
    __syncthreads();

    // --- QK^T: S[16q x 64k] per wave (C: row=q=crb+r, col=k=frow) ---
    f32x4 s[4];
#pragma unroll
    for (int n = 0; n < 4; ++n) {
      short8 kf0 = *(const short8*)&Ks[n * 16 + frow][fk8];
      short8 kf1 = *(const short8*)&Ks[n * 16 + frow][32 + fk8];
      f32x4 a = {};
      a = MFMA(qf[0], kf0, a);
      a = MFMA(qf[1], kf1, a);
      s[n] = a;
    }

    // --- scale + mask (mask is per-key; nonzero => -inf) ---
#pragma unroll
    for (int n = 0; n < 4; ++n) {
      const bool mk = mask[b * SEQ + kv0 + n * 16 + frow] != 0;
#pragma unroll
      for (int r = 0; r < 4; ++r)
        s[n][r] = mk ? -INFINITY : s[n][r] * 0.125f;
    }

    // --- online softmax (each 16-lane group owns 4 q-rows, k across lanes) ---
    float alpha[4];
#pragma unroll
    for (int r = 0; r < 4; ++r) {
      float mx = fmaxf(fmaxf(s[0][r], s[1][r]), fmaxf(s[2][r], s[3][r]));
      mx = fmaxf(mx, __shfl_xor(mx, 1));
      mx = fmaxf(mx, __shfl_xor(mx, 2));
      mx = fmaxf(mx, __shfl_xor(mx, 4));
      mx = fmaxf(mx, __shfl_xor(mx, 8));
      const float mn = fmaxf(m_run[r], mx);
      alpha[r] = __expf(m_run[r] - mn);
      m_run[r] = mn;
      float rs = 0.f;
#pragma unroll
      for (int n = 0; n < 4; ++n) {
        const float p = __expf(s[n][r] - mn);
        s[n][r] = p;
        rs += p;
      }
      rs += __shfl_xor(rs, 1);
      rs += __shfl_xor(rs, 2);
      rs += __shfl_xor(rs, 4);
      rs += __shfl_xor(rs, 8);
      l_run[r] = l_run[r] * alpha[r] + rs;
    }
#pragma unroll
    for (int d = 0; d < 4; ++d)
#pragma unroll
      for (int r = 0; r < 4; ++r)
        o[d][r] *= alpha[r];

    // --- P -> LDS (bf16) for PV A-fragments ---
#pragma unroll
    for (int n = 0; n < 4; ++n)
#pragma unroll
      for (int r = 0; r < 4; ++r)
        Ps[w][crb + r][n * 16 + frow] = f2bf(s[n][r]);
    asm volatile("s_waitcnt lgkmcnt(0)" ::: "memory");
    __builtin_amdgcn_sched_barrier(0);

    // --- PV: O[16q x 64d] += P @ V ---
    short8 pa0 = *(const short8*)&Ps[w][frow][fk8];
    short8 pa1 = *(const short8*)&Ps[w][frow][32 + fk8];
#pragma unroll
    for (int d = 0; d < 4; ++d) {
      short8 vf0 = *(const short8*)&Vt[d * 16 + frow][fk8];
      short8 vf1 = *(const short8*)&Vt[d * 16 + frow][32 + fk8];
      o[d] = MFMA(pa0, vf0, o[d]);
      o[d] = MFMA(pa1, vf1, o[d]);
    }
    __syncthreads();
  }

  // --- epilogue: divide by softmax denom, store bf16 ---
#pragma unroll
  for (int r = 0; r < 4; ++r) {
    const float inv = (l_run[r] > 0.f) ? 1.f / l_run[r] : 0.f;
#pragma unroll
    for (int d = 0; d < 4; ++d)
      O[(tok0 + q0 + crb + r) * DM + hc + d * 16 + frow] = f2bf(o[d][r] * inv);
  }
}

// ---------------------------------------------------------------------------
extern "C" void kernel_launch(void* const* d_in, const int* in_sizes, int n_in,
                              void* d_out, int out_size, void* d_ws, size_t ws_size,
                              hipStream_t stream) {
  const float* query = (const float*)d_in[0];
  const float* key_  = (const float*)d_in[1];
  const float* value = (const float*)d_in[2];
  const int* mask    = (const int*)d_in[3];
  const float* wq = (const float*)d_in[4];
  const float* wk = (const float*)d_in[5];
  const float* wv = (const float*)d_in[6];
  const float* wo = (const float*)d_in[7];
  float* out = (float*)d_out;
  char* ws = (char*)d_ws;

  // ws layout (bytes):
  // [0,6M)   Wt_QKV (bf16, transposed)
  // [6M,8M)  Wt_O
  // [8M,32M) x_q|x_k|x_v (bf16 converted inputs)
  // [32M,56M) Q|K|V projections (bf16)
  // [56M,64M) attn out (bf16)
  u16* wt_qkv = (u16*)(ws);
  u16* wt_o   = (u16*)(ws + (6u << 20));
  u16* xin    = (u16*)(ws + (8u << 20));
  u16* qkv    = (u16*)(ws + (32u << 20));
  u16* attn_o = (u16*)(ws + (56u << 20));

  transpose4<<<dim3(16, 16, 4), 256, 0, stream>>>(
      wq, wk, wv, wo,
      wt_qkv, wt_qkv + (size_t)DM * DM, wt_qkv + (size_t)2 * DM * DM, wt_o);

  conv3<<<dim3(2048, 1, 3), 256, 0, stream>>>(query, key_, value, xin);

  gemm_qkv<<<dim3(DM / 128, (NB * SEQ) / 128, 3), 256, 0, stream>>>(
      xin, wt_qkv, qkv);

  attn<<<dim3(NB * NH * (SEQ / 64)), 256, 0, stream>>>(
      qkv, qkv + (size_t)(NB * SEQ) * DM, qkv + (size_t)2 * (NB * SEQ) * DM,
      mask, attn_o);

  gemm_out<<<dim3(DM / 128, (NB * SEQ) / 128), 256, 0, stream>>>(
      attn_o, wt_o, out);
}

// Round 3
// 304.237 us; speedup vs baseline: 1.0670x; 1.0670x over previous
//
#include <hip/hip_runtime.h>
#include <hip/hip_bf16.h>
#include <stdint.h>

#define DM  1024
#define SEQ 2048
#define NB  2
#define NH  16
#define DKH 64
#define SCL 0.18033688f  // (1/sqrt(64)) * log2(e)  — softmax in exp2 domain

typedef unsigned short u16;
typedef __attribute__((ext_vector_type(8))) short short8;
typedef __attribute__((ext_vector_type(4))) float f32x4;

#define MFMA(a,b,c) __builtin_amdgcn_mfma_f32_16x16x32_bf16((a),(b),(c),0,0,0)

__device__ __forceinline__ void async_g2l16(const void* g, void* l) {
  __builtin_amdgcn_global_load_lds(
      (const __attribute__((address_space(1))) uint32_t*)g,
      (__attribute__((address_space(3))) uint32_t*)l, 16, 0, 0);
}

__device__ __forceinline__ u16 f2bf(float f) {
  uint32_t u = __builtin_bit_cast(uint32_t, f);
  u += 0x7fffu + ((u >> 16) & 1u);
  return (u16)(u >> 16);
}

// swizzled LDS helpers: logical (row, col-byte) over 128B rows, XOR bit4-6
__device__ __forceinline__ short8 lds_sw(const char* base, int row, int cb) {
  return *(const short8*)(base + row * 128 + (cb ^ ((row & 7) << 4)));
}
__device__ __forceinline__ void pw16(char* base, int row, int cb, u16 v) {
  *(u16*)(base + row * 128 + (cb ^ ((row & 7) << 4))) = v;
}

// ---------------------------------------------------------------------------
// f32 -> bf16 convert for q/k/v (grid.z selects tensor). 8 elems/thread.
// ---------------------------------------------------------------------------
__global__ __launch_bounds__(256) void conv3(
    const float* __restrict__ a0, const float* __restrict__ a1,
    const float* __restrict__ a2, u16* __restrict__ out) {
  const int z = blockIdx.z;
  const float* A = (z == 0) ? a0 : (z == 1) ? a1 : a2;
  u16* O = out + (size_t)z * NB * SEQ * DM;
  const size_t i = (size_t)blockIdx.x * 256 + threadIdx.x;
  const float4 a = ((const float4*)A)[i * 2];
  const float4 b = ((const float4*)A)[i * 2 + 1];
  u16 v[8] __attribute__((aligned(16)));
  v[0] = f2bf(a.x); v[1] = f2bf(a.y); v[2] = f2bf(a.z); v[3] = f2bf(a.w);
  v[4] = f2bf(b.x); v[5] = f2bf(b.y); v[6] = f2bf(b.z); v[7] = f2bf(b.w);
  *(uint4*)(O + i * 8) = *(uint4*)v;
}

// ---------------------------------------------------------------------------
// Weight transpose + convert: Wt[n][k] = bf16(W[k][n]), 1024x1024 f32 in.
// ---------------------------------------------------------------------------
__global__ __launch_bounds__(256) void transpose4(
    const float* __restrict__ w0, const float* __restrict__ w1,
    const float* __restrict__ w2, const float* __restrict__ w3,
    u16* __restrict__ o0, u16* __restrict__ o1,
    u16* __restrict__ o2, u16* __restrict__ o3) {
  __shared__ u16 tile[64][65];
  const int z = blockIdx.z;
  const float* W = (z == 0) ? w0 : (z == 1) ? w1 : (z == 2) ? w2 : w3;
  u16* O         = (z == 0) ? o0 : (z == 1) ? o1 : (z == 2) ? o2 : o3;
  const int k0 = blockIdx.x * 64, n0 = blockIdx.y * 64;
  const int t = threadIdx.x;
  const int r = t >> 2, cg = (t & 3) * 16;

  const float* src = W + (size_t)(k0 + r) * DM + n0 + cg;
#pragma unroll
  for (int j = 0; j < 4; ++j) {
    const float4 a = ((const float4*)src)[j];
    tile[r][cg + j * 4 + 0] = f2bf(a.x);
    tile[r][cg + j * 4 + 1] = f2bf(a.y);
    tile[r][cg + j * 4 + 2] = f2bf(a.z);
    tile[r][cg + j * 4 + 3] = f2bf(a.w);
  }
  __syncthreads();
  u16 u[16] __attribute__((aligned(16)));
#pragma unroll
  for (int j = 0; j < 16; ++j) u[j] = tile[cg + j][r];
  u16* dst = O + (size_t)(n0 + r) * DM + k0 + cg;
  *(uint4*)&dst[0] = *(uint4*)&u[0];
  *(uint4*)&dst[8] = *(uint4*)&u[8];
}

// ---------------------------------------------------------------------------
// V transpose (bf16): Vin[4096 tok][1024 dm] -> Vt[b][1024 dm][2048 tok]
// ---------------------------------------------------------------------------
__global__ __launch_bounds__(256) void vtrans(
    const u16* __restrict__ Vin, u16* __restrict__ Vt) {
  __shared__ u16 tile[64][65];
  const int tokT = blockIdx.x;   // 0..63
  const int dmT  = blockIdx.y;   // 0..15
  const int t = threadIdx.x;
  const int r = t >> 2, cg = (t & 3) * 16;
  const u16* src = Vin + (size_t)(tokT * 64 + r) * DM + dmT * 64 + cg;
  u16 v[16] __attribute__((aligned(16)));
  *(uint4*)&v[0] = *(const uint4*)src;
  *(uint4*)&v[8] = *(const uint4*)(src + 8);
#pragma unroll
  for (int j = 0; j < 16; ++j) tile[r][cg + j] = v[j];
  __syncthreads();
  u16 u[16] __attribute__((aligned(16)));
#pragma unroll
  for (int j = 0; j < 16; ++j) u[j] = tile[cg + j][r];
  const int b = (tokT * 64) >> 11;
  const int tok_in_b = (tokT * 64) & 2047;
  u16* dst = Vt + ((size_t)b * DM + dmT * 64 + r) * SEQ + tok_in_b + cg;
  *(uint4*)&dst[0] = *(uint4*)&u[0];
  *(uint4*)&dst[8] = *(uint4*)&u[8];
}

// ---------------------------------------------------------------------------
// GEMM: C[M][N] = A[M][K] @ Bt[N][K]^T, bf16 in, f32 accum. 128x128, BK=64.
// ---------------------------------------------------------------------------
template <int OUT_F32>
__device__ __forceinline__ void gemm128_body(
    const u16* __restrict__ A, const u16* __restrict__ Bt, void* __restrict__ Cv,
    int M, int N, int K, int bx, int by) {
  __shared__ u16 As[128 * 64];
  __shared__ u16 Bs[128 * 64];
  const int m0 = by * 128, n0 = bx * 128;
  const int t = threadIdx.x, w = t >> 6, l = t & 63;
  const int wr = w >> 1, wc = w & 1;
  const int frow = l & 15, fk8 = (l >> 4) * 8;
  f32x4 acc[4][4] = {};

  for (int k0 = 0; k0 < K; k0 += 64) {
#pragma unroll
    for (int i = 0; i < 4; ++i) {
      const int base = (i * 4 + w) * 1024;
      const int e = (base >> 1) + l * 8;
      const int row = e >> 6, col = e & 63;
      async_g2l16(A + (size_t)(m0 + row) * K + k0 + col, (char*)As + base);
      async_g2l16(Bt + (size_t)(n0 + row) * K + k0 + col, (char*)Bs + base);
    }
    __syncthreads();
#pragma unroll
    for (int kk = 0; kk < 2; ++kk) {
      short8 af[4], bf[4];
#pragma unroll
      for (int mi = 0; mi < 4; ++mi)
        af[mi] = *(const short8*)&As[(wr * 64 + mi * 16 + frow) * 64 + kk * 32 + fk8];
#pragma unroll
      for (int ni = 0; ni < 4; ++ni)
        bf[ni] = *(const short8*)&Bs[(wc * 64 + ni * 16 + frow) * 64 + kk * 32 + fk8];
#pragma unroll
      for (int mi = 0; mi < 4; ++mi)
#pragma unroll
        for (int ni = 0; ni < 4; ++ni)
          acc[mi][ni] = MFMA(af[mi], bf[ni], acc[mi][ni]);
    }
    __syncthreads();
  }

  const int crb = (l >> 4) * 4;
  for (int mi = 0; mi < 4; ++mi)
    for (int ni = 0; ni < 4; ++ni)
#pragma unroll
      for (int r = 0; r < 4; ++r) {
        const int row = m0 + wr * 64 + mi * 16 + crb + r;
        const int col = n0 + wc * 64 + ni * 16 + frow;
        if (OUT_F32) ((float*)Cv)[(size_t)row * N + col] = acc[mi][ni][r];
        else         ((u16*)Cv)[(size_t)row * N + col] = f2bf(acc[mi][ni][r]);
      }
}

__global__ __launch_bounds__(256) void gemm_qkv(
    const u16* __restrict__ xin, const u16* __restrict__ wt, u16* __restrict__ out) {
  const int z = blockIdx.z;
  gemm128_body<0>(xin + (size_t)z * NB * SEQ * DM, wt + (size_t)z * DM * DM,
                  out + (size_t)z * NB * SEQ * DM,
                  NB * SEQ, DM, DM, blockIdx.x, blockIdx.y);
}

__global__ __launch_bounds__(256) void gemm_out(
    const u16* __restrict__ A, const u16* __restrict__ Bt, float* __restrict__ C) {
  gemm128_body<1>(A, Bt, C, NB * SEQ, DM, DM, blockIdx.x, blockIdx.y);
}

// ---------------------------------------------------------------------------
// Flash attention v2. 256 thr (4 waves), 128 q/block (32/wave), KV tile 64.
// K and V^T staged via global_load_lds into XOR-swizzled [64][128B] tiles,
// double-buffered (2-phase pipeline). Softmax: exp2 domain; row-sum via MFMA
// against all-ones B fragment (rides the alpha rescale with O).
// ---------------------------------------------------------------------------
__global__ __launch_bounds__(256) void attn(
    const u16* __restrict__ Q, const u16* __restrict__ Kmat,
    const u16* __restrict__ VtG, const int* __restrict__ mask,
    u16* __restrict__ O) {
  __shared__ uint4 ldsv[49152 / 16];
  char* lds = (char*)ldsv;
  char* KB = lds;              // [2][8192]
  char* VB = lds + 16384;      // [2][8192]
  char* PB = lds + 32768;      // [4][4096]

  const int bid = blockIdx.x;
  const int qt = bid & 15;
  const int h  = (bid >> 4) & 15;
  const int b  = bid >> 8;
  const int t = threadIdx.x, w = t >> 6, l = t & 63;
  const int frow = l & 15, fk8 = (l >> 4) * 8, crb = (l >> 4) * 4;
  const size_t tok0 = (size_t)b * SEQ;
  const int q0 = qt * 128 + w * 32;
  const int hc = h * DKH;
  char* PW = PB + w * 4096;

  // staging geometry: per-lane pre-swizzled source offsets (tile-invariant)
  const int T0 = w * 2048 + l * 16;
  const int T1 = T0 + 1024;
  const int r0 = T0 >> 7, r1 = T1 >> 7;
  const int c0 = (T0 & 127) ^ ((r0 & 7) << 4);
  const int c1 = (T1 & 127) ^ ((r1 & 7) << 4);
  const u16* Kg = Kmat + tok0 * DM + hc;
  const u16* Vg = VtG + ((size_t)b * DM + hc) * SEQ;

  short8 qf[2][2];
#pragma unroll
  for (int qh = 0; qh < 2; ++qh)
#pragma unroll
    for (int ks = 0; ks < 2; ++ks)
      qf[qh][ks] = *(const short8*)(Q + (tok0 + q0 + qh * 16 + frow) * DM + hc + ks * 32 + fk8);

  const short ONE = 0x3F80;
  const short8 ONES = {ONE, ONE, ONE, ONE, ONE, ONE, ONE, ONE};

  f32x4 o[2][4] = {};
  f32x4 ol[2] = {};
  float m_run[2][4];
#pragma unroll
  for (int qh = 0; qh < 2; ++qh)
#pragma unroll
    for (int r = 0; r < 4; ++r) m_run[qh][r] = -1e30f;

  // prologue: stage tile 0 into buf 0
  async_g2l16((const char*)(Kg + (size_t)r0 * DM) + c0, KB + w * 2048);
  async_g2l16((const char*)(Kg + (size_t)r1 * DM) + c1, KB + w * 2048 + 1024);
  async_g2l16((const char*)(Vg + (size_t)r0 * SEQ) + c0, VB + w * 2048);
  async_g2l16((const char*)(Vg + (size_t)r1 * SEQ) + c1, VB + w * 2048 + 1024);

  int cur = 0;
  for (int it = 0; it < SEQ / 64; ++it) {
    const int kv0 = it * 64;
    asm volatile("s_waitcnt vmcnt(0)" ::: "memory");
    __syncthreads();
    if (it + 1 < SEQ / 64) {
      const int nkv = kv0 + 64;
      char* kd = KB + (cur ^ 1) * 8192 + w * 2048;
      char* vd = VB + (cur ^ 1) * 8192 + w * 2048;
      async_g2l16((const char*)(Kg + (size_t)(nkv + r0) * DM) + c0, kd);
      async_g2l16((const char*)(Kg + (size_t)(nkv + r1) * DM) + c1, kd + 1024);
      async_g2l16((const char*)(Vg + (size_t)r0 * SEQ + nkv) + c0, vd);
      async_g2l16((const char*)(Vg + (size_t)r1 * SEQ + nkv) + c1, vd + 1024);
    }
    const char* Kt = KB + cur * 8192;
    const char* Vt = VB + cur * 8192;

    // ---- QK^T ----
    f32x4 s[2][4];
#pragma unroll
    for (int n = 0; n < 4; ++n) {
      short8 kf0 = lds_sw(Kt, n * 16 + frow, fk8 * 2);
      short8 kf1 = lds_sw(Kt, n * 16 + frow, 64 + fk8 * 2);
#pragma unroll
      for (int qh = 0; qh < 2; ++qh) {
        f32x4 a = {};
        a = MFMA(qf[qh][0], kf0, a);
        a = MFMA(qf[qh][1], kf1, a);
        s[qh][n] = a;
      }
    }

    // ---- mask + scale (exp2 domain) ----
#pragma unroll
    for (int n = 0; n < 4; ++n) {
      const int mk = mask[b * SEQ + kv0 + n * 16 + frow];
#pragma unroll
      for (int qh = 0; qh < 2; ++qh)
#pragma unroll
        for (int r = 0; r < 4; ++r)
          s[qh][n][r] = mk ? -INFINITY : s[qh][n][r] * SCL;
    }

    // ---- online softmax ----
#pragma unroll
    for (int qh = 0; qh < 2; ++qh) {
      float alpha[4];
#pragma unroll
      for (int r = 0; r < 4; ++r) {
        float mx = fmaxf(fmaxf(s[qh][0][r], s[qh][1][r]), fmaxf(s[qh][2][r], s[qh][3][r]));
        mx = fmaxf(mx, __shfl_xor(mx, 1));
        mx = fmaxf(mx, __shfl_xor(mx, 2));
        mx = fmaxf(mx, __shfl_xor(mx, 4));
        mx = fmaxf(mx, __shfl_xor(mx, 8));
        const float mn = fmaxf(m_run[qh][r], mx);
        alpha[r] = exp2f(m_run[qh][r] - mn);
        m_run[qh][r] = mn;
#pragma unroll
        for (int n = 0; n < 4; ++n)
          s[qh][n][r] = exp2f(s[qh][n][r] - mn);
      }
#pragma unroll
      for (int r = 0; r < 4; ++r) ol[qh][r] *= alpha[r];
#pragma unroll
      for (int d = 0; d < 4; ++d)
#pragma unroll
        for (int r = 0; r < 4; ++r) o[qh][d][r] *= alpha[r];
#pragma unroll
      for (int n = 0; n < 4; ++n)
#pragma unroll
        for (int r = 0; r < 4; ++r)
          pw16(PW, qh * 16 + crb + r, (n * 16 + frow) * 2, f2bf(s[qh][n][r]));
    }
    asm volatile("s_waitcnt lgkmcnt(0)" ::: "memory");
    __builtin_amdgcn_sched_barrier(0);

    // ---- PV + row-sum via ones-MFMA ----
    short8 pa[2][2];
#pragma unroll
    for (int qh = 0; qh < 2; ++qh) {
      pa[qh][0] = lds_sw(PW, qh * 16 + frow, fk8 * 2);
      pa[qh][1] = lds_sw(PW, qh * 16 + frow, 64 + fk8 * 2);
      ol[qh] = MFMA(pa[qh][1], ONES, MFMA(pa[qh][0], ONES, ol[qh]));
    }
#pragma unroll
    for (int d = 0; d < 4; ++d) {
      short8 vf0 = lds_sw(Vt, d * 16 + frow, fk8 * 2);
      short8 vf1 = lds_sw(Vt, d * 16 + frow, 64 + fk8 * 2);
#pragma unroll
      for (int qh = 0; qh < 2; ++qh)
        o[qh][d] = MFMA(pa[qh][1], vf1, MFMA(pa[qh][0], vf0, o[qh][d]));
    }
    cur ^= 1;
  }

  // ---- epilogue ----
#pragma unroll
  for (int qh = 0; qh < 2; ++qh)
#pragma unroll
    for (int r = 0; r < 4; ++r) {
      const float den = ol[qh][r];
      const float inv = den > 0.f ? 1.f / den : 0.f;
#pragma unroll
      for (int d = 0; d < 4; ++d)
        O[(tok0 + q0 + qh * 16 + crb + r) * DM + hc + d * 16 + frow] = f2bf(o[qh][d][r] * inv);
    }
}

// ---------------------------------------------------------------------------
extern "C" void kernel_launch(void* const* d_in, const int* in_sizes, int n_in,
                              void* d_out, int out_size, void* d_ws, size_t ws_size,
                              hipStream_t stream) {
  const float* query = (const float*)d_in[0];
  const float* key_  = (const float*)d_in[1];
  const float* value = (const float*)d_in[2];
  const int* mask    = (const int*)d_in[3];
  const float* wq = (const float*)d_in[4];
  const float* wk = (const float*)d_in[5];
  const float* wv = (const float*)d_in[6];
  const float* wo = (const float*)d_in[7];
  float* out = (float*)d_out;
  char* ws = (char*)d_ws;

  // ws layout (bytes):
  // [0,6M)    Wt_QKV (bf16, transposed)
  // [6M,8M)   Wt_O
  // [8M,32M)  xin (bf16 q|k|v inputs)  — dead after gemm_qkv:
  //   [8M,16M)  VtG (per-b transposed V) overwrites it
  //   [16M,24M) attn_o
  // [32M,56M) Q|K|V projections (bf16)
  u16* wt_qkv = (u16*)(ws);
  u16* wt_o   = (u16*)(ws + (6u << 20));
  u16* xin    = (u16*)(ws + (8u << 20));
  u16* vtg    = (u16*)(ws + (8u << 20));
  u16* attn_o = (u16*)(ws + (16u << 20));
  u16* qkv    = (u16*)(ws + (32u << 20));

  transpose4<<<dim3(16, 16, 4), 256, 0, stream>>>(
      wq, wk, wv, wo,
      wt_qkv, wt_qkv + (size_t)DM * DM, wt_qkv + (size_t)2 * DM * DM, wt_o);

  conv3<<<dim3(2048, 1, 3), 256, 0, stream>>>(query, key_, value, xin);

  gemm_qkv<<<dim3(DM / 128, (NB * SEQ) / 128, 3), 256, 0, stream>>>(
      xin, wt_qkv, qkv);

  vtrans<<<dim3(64, 16), 256, 0, stream>>>(
      qkv + (size_t)2 * NB * SEQ * DM, vtg);

  attn<<<dim3(NB * NH * (SEQ / 128)), 256, 0, stream>>>(
      qkv, qkv + (size_t)NB * SEQ * DM, vtg, mask, attn_o);

  gemm_out<<<dim3(DM / 128, (NB * SEQ) / 128), 256, 0, stream>>>(
      attn_o, wt_o, out);
}

// Round 5
// 237.963 us; speedup vs baseline: 1.3641x; 1.2785x over previous
//
#include <hip/hip_runtime.h>
#include <hip/hip_bf16.h>
#include <stdint.h>

#define DM  1024
#define SEQ 2048
#define NB  2
#define NH  16
#define DKH 64
#define SCL 0.18033688f  // (1/sqrt(64)) * log2(e)  — softmax in exp2 domain

typedef unsigned short u16;
typedef __attribute__((ext_vector_type(8))) short short8;
typedef __attribute__((ext_vector_type(4))) float f32x4;

#define MFMA(a,b,c) __builtin_amdgcn_mfma_f32_16x16x32_bf16((a),(b),(c),0,0,0)

__device__ __forceinline__ void async_g2l16(const void* g, void* l) {
  __builtin_amdgcn_global_load_lds(
      (const __attribute__((address_space(1))) uint32_t*)g,
      (__attribute__((address_space(3))) uint32_t*)l, 16, 0, 0);
}

__device__ __forceinline__ u16 f2bf(float f) {
  uint32_t u = __builtin_bit_cast(uint32_t, f);
  u += 0x7fffu + ((u >> 16) & 1u);
  return (u16)(u >> 16);
}

// swizzled LDS read: logical (row, col-byte) over 128B rows, XOR bits 4-6
__device__ __forceinline__ short8 lds_sw(const char* base, int row, int cb) {
  return *(const short8*)(base + row * 128 + (cb ^ ((row & 7) << 4)));
}

// ---------------------------------------------------------------------------
// f32 -> bf16 convert for q/k/v (grid.z selects tensor). 8 elems/thread.
// ---------------------------------------------------------------------------
__global__ __launch_bounds__(256) void conv3(
    const float* __restrict__ a0, const float* __restrict__ a1,
    const float* __restrict__ a2, u16* __restrict__ out) {
  const int z = blockIdx.z;
  const float* A = (z == 0) ? a0 : (z == 1) ? a1 : a2;
  u16* O = out + (size_t)z * NB * SEQ * DM;
  const size_t i = (size_t)blockIdx.x * 256 + threadIdx.x;
  const float4 a = ((const float4*)A)[i * 2];
  const float4 b = ((const float4*)A)[i * 2 + 1];
  u16 v[8] __attribute__((aligned(16)));
  v[0] = f2bf(a.x); v[1] = f2bf(a.y); v[2] = f2bf(a.z); v[3] = f2bf(a.w);
  v[4] = f2bf(b.x); v[5] = f2bf(b.y); v[6] = f2bf(b.z); v[7] = f2bf(b.w);
  *(uint4*)(O + i * 8) = *(uint4*)v;
}

// ---------------------------------------------------------------------------
// Weight transpose + convert: Wt[n][k] = bf16(W[k][n]), 1024x1024 f32 in.
// ---------------------------------------------------------------------------
__global__ __launch_bounds__(256) void transpose4(
    const float* __restrict__ w0, const float* __restrict__ w1,
    const float* __restrict__ w2, const float* __restrict__ w3,
    u16* __restrict__ o0, u16* __restrict__ o1,
    u16* __restrict__ o2, u16* __restrict__ o3) {
  __shared__ u16 tile[64][65];
  const int z = blockIdx.z;
  const float* W = (z == 0) ? w0 : (z == 1) ? w1 : (z == 2) ? w2 : w3;
  u16* O         = (z == 0) ? o0 : (z == 1) ? o1 : (z == 2) ? o2 : o3;
  const int k0 = blockIdx.x * 64, n0 = blockIdx.y * 64;
  const int t = threadIdx.x;
  const int r = t >> 2, cg = (t & 3) * 16;

  const float* src = W + (size_t)(k0 + r) * DM + n0 + cg;
#pragma unroll
  for (int j = 0; j < 4; ++j) {
    const float4 a = ((const float4*)src)[j];
    tile[r][cg + j * 4 + 0] = f2bf(a.x);
    tile[r][cg + j * 4 + 1] = f2bf(a.y);
    tile[r][cg + j * 4 + 2] = f2bf(a.z);
    tile[r][cg + j * 4 + 3] = f2bf(a.w);
  }
  __syncthreads();
  u16 u[16] __attribute__((aligned(16)));
#pragma unroll
  for (int j = 0; j < 16; ++j) u[j] = tile[cg + j][r];
  u16* dst = O + (size_t)(n0 + r) * DM + k0 + cg;
  *(uint4*)&dst[0] = *(uint4*)&u[0];
  *(uint4*)&dst[8] = *(uint4*)&u[8];
}

// ---------------------------------------------------------------------------
// Mask compaction: per batch, stable list of key positions with mask==0.
// idx[b][p] = kept token (pad -> 0), nkv[b] = count. 1 block per batch.
// ---------------------------------------------------------------------------
__global__ __launch_bounds__(256) void mask_scan(
    const int* __restrict__ mask, int* __restrict__ idx, int* __restrict__ nkv) {
  __shared__ int cnt[256];
  const int b = blockIdx.x, t = threadIdx.x;
  const int* mp = mask + b * SEQ + t * 8;
  int m[8], c = 0;
#pragma unroll
  for (int j = 0; j < 8; ++j) { m[j] = mp[j]; c += (m[j] == 0); }
  cnt[t] = c;
  __syncthreads();
  for (int off = 1; off < 256; off <<= 1) {
    int v = 0;
    if (t >= off) v = cnt[t - off];
    __syncthreads();
    if (t >= off) cnt[t] += v;
    __syncthreads();
  }
  int base = cnt[t] - c;  // exclusive prefix
  int* ip = idx + b * SEQ;
#pragma unroll
  for (int j = 0; j < 8; ++j)
    if (m[j] == 0) ip[base++] = t * 8 + j;
  const int total = cnt[255];
  if (t == 0) nkv[b] = total;
  for (int p = total + t; p < SEQ; p += 256) ip[p] = 0;
}

// ---------------------------------------------------------------------------
// V gather-transpose: Vt[b][dm][pos] = Vproj[b][idx[b][pos]][dm]
// ---------------------------------------------------------------------------
__global__ __launch_bounds__(256) void vtransg(
    const u16* __restrict__ Vin, const int* __restrict__ idx, u16* __restrict__ Vt) {
  __shared__ u16 tile[64][65];
  const int posT = blockIdx.x;   // 0..31
  const int dmT  = blockIdx.y;   // 0..15
  const int b    = blockIdx.z;
  const int t = threadIdx.x;
  const int r = t >> 2, cg = (t & 3) * 16;
  const int srow = idx[b * SEQ + posT * 64 + r];
  const u16* src = Vin + ((size_t)b * SEQ + srow) * DM + dmT * 64 + cg;
  u16 v[16] __attribute__((aligned(16)));
  *(uint4*)&v[0] = *(const uint4*)src;
  *(uint4*)&v[8] = *(const uint4*)(src + 8);
#pragma unroll
  for (int j = 0; j < 16; ++j) tile[r][cg + j] = v[j];
  __syncthreads();
  u16 u[16] __attribute__((aligned(16)));
#pragma unroll
  for (int j = 0; j < 16; ++j) u[j] = tile[cg + j][r];
  u16* dst = Vt + ((size_t)b * DM + dmT * 64 + r) * SEQ + posT * 64 + cg;
  *(uint4*)&dst[0] = *(uint4*)&u[0];
  *(uint4*)&dst[8] = *(uint4*)&u[8];
}

// ---------------------------------------------------------------------------
// GEMM: C[M][N] = A[M][K] @ Bt[N][K]^T, bf16 in, f32 accum. 128x128, BK=64.
// ---------------------------------------------------------------------------
template <int OUT_F32>
__device__ __forceinline__ void gemm128_body(
    const u16* __restrict__ A, const u16* __restrict__ Bt, void* __restrict__ Cv,
    int M, int N, int K, int bx, int by) {
  __shared__ u16 As[128 * 64];
  __shared__ u16 Bs[128 * 64];
  const int m0 = by * 128, n0 = bx * 128;
  const int t = threadIdx.x, w = t >> 6, l = t & 63;
  const int wr = w >> 1, wc = w & 1;
  const int frow = l & 15, fk8 = (l >> 4) * 8;
  f32x4 acc[4][4] = {};

  for (int k0 = 0; k0 < K; k0 += 64) {
#pragma unroll
    for (int i = 0; i < 4; ++i) {
      const int base = (i * 4 + w) * 1024;
      const int e = (base >> 1) + l * 8;
      const int row = e >> 6, col = e & 63;
      async_g2l16(A + (size_t)(m0 + row) * K + k0 + col, (char*)As + base);
      async_g2l16(Bt + (size_t)(n0 + row) * K + k0 + col, (char*)Bs + base);
    }
    __syncthreads();
#pragma unroll
    for (int kk = 0; kk < 2; ++kk) {
      short8 af[4], bf[4];
#pragma unroll
      for (int mi = 0; mi < 4; ++mi)
        af[mi] = *(const short8*)&As[(wr * 64 + mi * 16 + frow) * 64 + kk * 32 + fk8];
#pragma unroll
      for (int ni = 0; ni < 4; ++ni)
        bf[ni] = *(const short8*)&Bs[(wc * 64 + ni * 16 + frow) * 64 + kk * 32 + fk8];
#pragma unroll
      for (int mi = 0; mi < 4; ++mi)
#pragma unroll
        for (int ni = 0; ni < 4; ++ni)
          acc[mi][ni] = MFMA(af[mi], bf[ni], acc[mi][ni]);
    }
    __syncthreads();
  }

  const int crb = (l >> 4) * 4;
  for (int mi = 0; mi < 4; ++mi)
    for (int ni = 0; ni < 4; ++ni)
#pragma unroll
      for (int r = 0; r < 4; ++r) {
        const int row = m0 + wr * 64 + mi * 16 + crb + r;
        const int col = n0 + wc * 64 + ni * 16 + frow;
        if (OUT_F32) ((float*)Cv)[(size_t)row * N + col] = acc[mi][ni][r];
        else         ((u16*)Cv)[(size_t)row * N + col] = f2bf(acc[mi][ni][r]);
      }
}

__global__ __launch_bounds__(256) void gemm_qkv(
    const u16* __restrict__ xin, const u16* __restrict__ wt, u16* __restrict__ out) {
  const int z = blockIdx.z;
  gemm128_body<0>(xin + (size_t)z * NB * SEQ * DM, wt + (size_t)z * DM * DM,
                  out + (size_t)z * NB * SEQ * DM,
                  NB * SEQ, DM, DM, blockIdx.x, blockIdx.y);
}

__global__ __launch_bounds__(256) void gemm_out(
    const u16* __restrict__ A, const u16* __restrict__ Bt, float* __restrict__ C) {
  gemm128_body<1>(A, Bt, C, NB * SEQ, DM, DM, blockIdx.x, blockIdx.y);
}

// ---------------------------------------------------------------------------
// Flash attention v3: compacted keys. 256 thr (4 waves), 64 q/block (16/wave),
// dynamic tile count = ceil(nkv/64). K gathered in-kernel via idx (per-lane
// global_load_lds sources), V^T pre-gathered. exp2-domain softmax with
// negm folded into the scale FMA; defer-max (THR=8); truncated P->bf16;
// row-sum via ones-MFMA.
// ---------------------------------------------------------------------------
__global__ __launch_bounds__(256) void attn(
    const u16* __restrict__ Q, const u16* __restrict__ Kp,
    const u16* __restrict__ Vtc, const int* __restrict__ idx,
    const int* __restrict__ nkv, u16* __restrict__ O) {
  __shared__ uint4 ldsv[40960 / 16];
  char* lds = (char*)ldsv;
  char* KB = lds;              // [2][8192]
  char* VB = lds + 16384;      // [2][8192]
  char* PB = lds + 32768;      // [4][2048]

  const int bid = blockIdx.x;
  const int qt = bid & 31;
  const int h  = (bid >> 5) & 15;
  const int b  = bid >> 9;
  const int t = threadIdx.x, w = t >> 6, l = t & 63;
  const int frow = l & 15, fk8 = (l >> 4) * 8, crb = (l >> 4) * 4;
  const size_t tok0 = (size_t)b * SEQ;
  const int q0 = qt * 64 + w * 16;
  const int hc = h * DKH;
  char* PW = PB + w * 2048;

  const int nk = nkv[b];
  const int nt = (nk + 63) >> 6;

  // staging geometry (pre-swizzled source offsets, tile-invariant)
  const int T0 = w * 2048 + l * 16;
  const int T1 = T0 + 1024;
  const int r0 = T0 >> 7, r1 = T1 >> 7;
  const int c0 = (T0 & 127) ^ ((r0 & 7) << 4);
  const int c1 = (T1 & 127) ^ ((r1 & 7) << 4);
  const u16* Kg = Kp + tok0 * DM + hc;
  const u16* Vg = Vtc + ((size_t)b * DM + hc) * SEQ;
  const int* ib = idx + b * SEQ;

  short8 qf[2];
#pragma unroll
  for (int ks = 0; ks < 2; ++ks)
    qf[ks] = *(const short8*)(Q + (tok0 + q0 + frow) * DM + hc + ks * 32 + fk8);

  const short ONE = 0x3F80;
  const short8 ONES = {ONE, ONE, ONE, ONE, ONE, ONE, ONE, ONE};

  f32x4 o[4] = {};
  f32x4 ol = {};
  float negm[4] = {-8.f, -8.f, -8.f, -8.f};

  // P write addresses (tile-invariant, swizzled)
  u16* pwa[4][4];
#pragma unroll
  for (int n = 0; n < 4; ++n)
#pragma unroll
    for (int r = 0; r < 4; ++r)
      pwa[n][r] = (u16*)(PW + (crb + r) * 128 +
                         ((((n * 16 + frow) * 2)) ^ (((crb + r) & 7) << 4)));

  // prologue: stage tile 0; preload idx rows for tile 1
  int ia0, ia1;
  if (nt > 0) {
    ia0 = ib[r0]; ia1 = ib[r1];
    async_g2l16((const char*)(Kg + (size_t)ia0 * DM) + c0, KB + w * 2048);
    async_g2l16((const char*)(Kg + (size_t)ia1 * DM) + c1, KB + w * 2048 + 1024);
    async_g2l16((const char*)(Vg + (size_t)r0 * SEQ) + c0, VB + w * 2048);
    async_g2l16((const char*)(Vg + (size_t)r1 * SEQ) + c1, VB + w * 2048 + 1024);
    ia0 = ib[(64 + r0) & 2047]; ia1 = ib[(64 + r1) & 2047];
  }

  int cur = 0;
  for (int it = 0; it < nt; ++it) {
    const int kv0 = it * 64;
    asm volatile("s_waitcnt vmcnt(0)" ::: "memory");
    __syncthreads();
    if (it + 1 < nt) {
      char* kd = KB + (cur ^ 1) * 8192 + w * 2048;
      char* vd = VB + (cur ^ 1) * 8192 + w * 2048;
      async_g2l16((const char*)(Kg + (size_t)ia0 * DM) + c0, kd);
      async_g2l16((const char*)(Kg + (size_t)ia1 * DM) + c1, kd + 1024);
      async_g2l16((const char*)(Vg + (size_t)r0 * SEQ + kv0 + 64) + c0, vd);
      async_g2l16((const char*)(Vg + (size_t)r1 * SEQ + kv0 + 64) + c1, vd + 1024);
      ia0 = ib[((it + 2) * 64 + r0) & 2047];
      ia1 = ib[((it + 2) * 64 + r1) & 2047];
    }
    const char* Kt = KB + cur * 8192;
    const char* Vt = VB + cur * 8192;

    // ---- QK^T + scale + negm fold ----
    f32x4 s[4];
#pragma unroll
    for (int n = 0; n < 4; ++n) {
      short8 kf0 = lds_sw(Kt, n * 16 + frow, fk8 * 2);
      short8 kf1 = lds_sw(Kt, n * 16 + frow, 64 + fk8 * 2);
      f32x4 a = {};
      a = MFMA(qf[0], kf0, a);
      a = MFMA(qf[1], kf1, a);
      s[n] = a;
    }
#pragma unroll
    for (int n = 0; n < 4; ++n)
#pragma unroll
      for (int r = 0; r < 4; ++r)
        s[n][r] = __builtin_fmaf(s[n][r], SCL, negm[r]);

    // ---- last-tile pad bias ----
    if (it == nt - 1) {
#pragma unroll
      for (int n = 0; n < 4; ++n) {
        const bool valid = (kv0 + n * 16 + frow) < nk;
#pragma unroll
        for (int r = 0; r < 4; ++r)
          s[n][r] = valid ? s[n][r] : -1e30f;
      }
    }

    // ---- defer-max: rescale only if some row max exceeds THR=8 ----
    float lm = fmaxf(fmaxf(fmaxf(s[0][0], s[0][1]), fmaxf(s[0][2], s[0][3])),
                     fmaxf(fmaxf(s[1][0], s[1][1]), fmaxf(s[1][2], s[1][3])));
    lm = fmaxf(lm, fmaxf(fmaxf(s[2][0], s[2][1]), fmaxf(s[2][2], s[2][3])));
    lm = fmaxf(lm, fmaxf(fmaxf(s[3][0], s[3][1]), fmaxf(s[3][2], s[3][3])));
    if (__any(lm > 8.0f)) {
#pragma unroll
      for (int r = 0; r < 4; ++r) {
        float mx = fmaxf(fmaxf(s[0][r], s[1][r]), fmaxf(s[2][r], s[3][r]));
        mx = fmaxf(mx, __shfl_xor(mx, 1));
        mx = fmaxf(mx, __shfl_xor(mx, 2));
        mx = fmaxf(mx, __shfl_xor(mx, 4));
        mx = fmaxf(mx, __shfl_xor(mx, 8));
        const float d = fmaxf(mx, 0.f);
        const float al = exp2f(-d);
        negm[r] -= d;
        ol[r] *= al;
#pragma unroll
        for (int dd = 0; dd < 4; ++dd) o[dd][r] *= al;
#pragma unroll
        for (int n = 0; n < 4; ++n) s[n][r] -= d;
      }
    }

    // ---- exp + truncated bf16 P write ----
#pragma unroll
    for (int n = 0; n < 4; ++n)
#pragma unroll
      for (int r = 0; r < 4; ++r) {
        const float p = exp2f(s[n][r]);
        *pwa[n][r] = (u16)(__builtin_bit_cast(uint32_t, p) >> 16);
      }
    asm volatile("s_waitcnt lgkmcnt(0)" ::: "memory");
    __builtin_amdgcn_sched_barrier(0);

    // ---- PV + row-sum via ones-MFMA ----
    short8 pa0 = lds_sw(PW, frow, fk8 * 2);
    short8 pa1 = lds_sw(PW, frow, 64 + fk8 * 2);
    ol = MFMA(pa1, ONES, MFMA(pa0, ONES, ol));
#pragma unroll
    for (int d = 0; d < 4; ++d) {
      short8 vf0 = lds_sw(Vt, d * 16 + frow, fk8 * 2);
      short8 vf1 = lds_sw(Vt, d * 16 + frow, 64 + fk8 * 2);
      o[d] = MFMA(pa1, vf1, MFMA(pa0, vf0, o[d]));
    }
    cur ^= 1;
  }

  // ---- epilogue ----
#pragma unroll
  for (int r = 0; r < 4; ++r) {
    const float den = ol[r];
    const float inv = den > 0.f ? 1.f / den : 0.f;
#pragma unroll
    for (int d = 0; d < 4; ++d)
      O[(tok0 + q0 + crb + r) * DM + hc + d * 16 + frow] = f2bf(o[d][r] * inv);
  }
}

// ---------------------------------------------------------------------------
extern "C" void kernel_launch(void* const* d_in, const int* in_sizes, int n_in,
                              void* d_out, int out_size, void* d_ws, size_t ws_size,
                              hipStream_t stream) {
  const float* query = (const float*)d_in[0];
  const float* key_  = (const float*)d_in[1];
  const float* value = (const float*)d_in[2];
  const int* mask    = (const int*)d_in[3];
  const float* wq = (const float*)d_in[4];
  const float* wk = (const float*)d_in[5];
  const float* wv = (const float*)d_in[6];
  const float* wo = (const float*)d_in[7];
  float* out = (float*)d_out;
  char* ws = (char*)d_ws;

  // ws layout (bytes):
  // [0,6M)    Wt_QKV (bf16, transposed)   [6M,8M)  Wt_O
  // [8M,32M)  xin (bf16 q|k|v) — live until gemm_qkv completes; AFTER that:
  //   [8M,16M)  Vtc (compacted transposed V)   [16M,24M) attn_o
  // [32M,56M) Q|K|V projections (bf16)
  // [56M,56M+16K) idx   [+16K,+8) nkv      (disjoint from everything above —
  //   round-4 bug: idx at 24M clobbered xin's V region before gemm_qkv ran)
  u16* wt_qkv = (u16*)(ws);
  u16* wt_o   = (u16*)(ws + (6u << 20));
  u16* xin    = (u16*)(ws + (8u << 20));
  u16* vtc    = (u16*)(ws + (8u << 20));
  u16* attn_o = (u16*)(ws + (16u << 20));
  u16* qkv    = (u16*)(ws + (32u << 20));
  int* idx    = (int*)(ws + (56u << 20));
  int* nkv    = (int*)(ws + (56u << 20) + 16384);

  transpose4<<<dim3(16, 16, 4), 256, 0, stream>>>(
      wq, wk, wv, wo,
      wt_qkv, wt_qkv + (size_t)DM * DM, wt_qkv + (size_t)2 * DM * DM, wt_o);

  conv3<<<dim3(2048, 1, 3), 256, 0, stream>>>(query, key_, value, xin);

  mask_scan<<<dim3(NB), 256, 0, stream>>>(mask, idx, nkv);

  gemm_qkv<<<dim3(DM / 128, (NB * SEQ) / 128, 3), 256, 0, stream>>>(
      xin, wt_qkv, qkv);

  vtransg<<<dim3(32, 16, NB), 256, 0, stream>>>(
      qkv + (size_t)2 * NB * SEQ * DM, idx, vtc);

  attn<<<dim3(NB * NH * (SEQ / 64)), 256, 0, stream>>>(
      qkv, qkv + (size_t)NB * SEQ * DM, vtc, idx, nkv, attn_o);

  gemm_out<<<dim3(DM / 128, (NB * SEQ) / 128), 256, 0, stream>>>(
      attn_o, wt_o, out);
}

// Round 6
// 223.106 us; speedup vs baseline: 1.4549x; 1.0666x over previous
//
#include <hip/hip_runtime.h>
#include <hip/hip_bf16.h>
#include <stdint.h>

#define DM  1024
#define SEQ 2048
#define NB  2
#define NH  16
#define DKH 64
#define SCL 0.18033688f  // (1/sqrt(64)) * log2(e)  — softmax in exp2 domain

typedef unsigned short u16;
typedef __attribute__((ext_vector_type(8))) short short8;
typedef __attribute__((ext_vector_type(4))) float f32x4;

#define MFMA(a,b,c) __builtin_amdgcn_mfma_f32_16x16x32_bf16((a),(b),(c),0,0,0)

__device__ __forceinline__ void async_g2l16(const void* g, void* l) {
  __builtin_amdgcn_global_load_lds(
      (const __attribute__((address_space(1))) uint32_t*)g,
      (__attribute__((address_space(3))) uint32_t*)l, 16, 0, 0);
}

__device__ __forceinline__ u16 f2bf(float f) {
  uint32_t u = __builtin_bit_cast(uint32_t, f);
  u += 0x7fffu + ((u >> 16) & 1u);
  return (u16)(u >> 16);
}

// swizzled LDS read: logical (row, col-byte) over 128B rows, XOR bits 4-6
__device__ __forceinline__ short8 lds_sw(const char* base, int row, int cb) {
  return *(const short8*)(base + row * 128 + (cb ^ ((row & 7) << 4)));
}

// ---------------------------------------------------------------------------
// prep: fused {weight transpose+convert | q/k/v f32->bf16 convert | mask scan}
// blocks [0,1024): transpose; [1024,7168): conv; [7168,7170): mask scan.
// ---------------------------------------------------------------------------
__global__ __launch_bounds__(256) void prep(
    const float* __restrict__ query, const float* __restrict__ key_,
    const float* __restrict__ value, const int* __restrict__ mask,
    const float* __restrict__ w0, const float* __restrict__ w1,
    const float* __restrict__ w2, const float* __restrict__ w3,
    u16* __restrict__ xin, u16* __restrict__ wt_qkv, u16* __restrict__ wt_o,
    int* __restrict__ idx, int* __restrict__ nkv) {
  __shared__ char shm[8320];
  const int bid = blockIdx.x;
  const int t = threadIdx.x;

  if (bid < 1024) {  // ---- weight transpose: Wt[n][k] = bf16(W[k][n]) ----
    u16 (*tile)[65] = (u16(*)[65])shm;
    const int z = bid >> 8, rem = bid & 255;
    const float* W = (z == 0) ? w0 : (z == 1) ? w1 : (z == 2) ? w2 : w3;
    u16* O = (z < 3) ? (wt_qkv + (size_t)z * DM * DM) : wt_o;
    const int k0 = (rem & 15) * 64, n0 = (rem >> 4) * 64;
    const int r = t >> 2, cg = (t & 3) * 16;
    const float* src = W + (size_t)(k0 + r) * DM + n0 + cg;
#pragma unroll
    for (int j = 0; j < 4; ++j) {
      const float4 a = ((const float4*)src)[j];
      tile[r][cg + j * 4 + 0] = f2bf(a.x);
      tile[r][cg + j * 4 + 1] = f2bf(a.y);
      tile[r][cg + j * 4 + 2] = f2bf(a.z);
      tile[r][cg + j * 4 + 3] = f2bf(a.w);
    }
    __syncthreads();
    u16 u[16] __attribute__((aligned(16)));
#pragma unroll
    for (int j = 0; j < 16; ++j) u[j] = tile[cg + j][r];
    u16* dst = O + (size_t)(n0 + r) * DM + k0 + cg;
    *(uint4*)&dst[0] = *(uint4*)&u[0];
    *(uint4*)&dst[8] = *(uint4*)&u[8];
  } else if (bid < 7168) {  // ---- f32 -> bf16 convert ----
    const int cb = bid - 1024;
    const int z = cb >> 11;
    const float* A = (z == 0) ? query : (z == 1) ? key_ : value;
    u16* O = xin + (size_t)z * NB * SEQ * DM;
    const size_t i = (size_t)(cb & 2047) * 256 + t;
    const float4 a = ((const float4*)A)[i * 2];
    const float4 b = ((const float4*)A)[i * 2 + 1];
    u16 v[8] __attribute__((aligned(16)));
    v[0] = f2bf(a.x); v[1] = f2bf(a.y); v[2] = f2bf(a.z); v[3] = f2bf(a.w);
    v[4] = f2bf(b.x); v[5] = f2bf(b.y); v[6] = f2bf(b.z); v[7] = f2bf(b.w);
    *(uint4*)(O + i * 8) = *(uint4*)v;
  } else {  // ---- mask compaction scan ----
    int* cnt = (int*)shm;
    const int b = bid - 7168;
    const int* mp = mask + b * SEQ + t * 8;
    int m[8], c = 0;
#pragma unroll
    for (int j = 0; j < 8; ++j) { m[j] = mp[j]; c += (m[j] == 0); }
    cnt[t] = c;
    __syncthreads();
    for (int off = 1; off < 256; off <<= 1) {
      int v = 0;
      if (t >= off) v = cnt[t - off];
      __syncthreads();
      if (t >= off) cnt[t] += v;
      __syncthreads();
    }
    int base = cnt[t] - c;
    int* ip = idx + b * SEQ;
#pragma unroll
    for (int j = 0; j < 8; ++j)
      if (m[j] == 0) ip[base++] = t * 8 + j;
    const int total = cnt[255];
    if (t == 0) nkv[b] = total;
    for (int p = total + t; p < SEQ; p += 256) ip[p] = 0;
  }
}

// ---------------------------------------------------------------------------
// kvprep: fused {V gather-transpose | K gather}.
// blocks [0,1024): Vt[b][dm][pos]=V[b][idx[pos]][dm]; [1024,1152): K gather.
// ---------------------------------------------------------------------------
__global__ __launch_bounds__(256) void kvprep(
    const u16* __restrict__ Kin, const u16* __restrict__ Vin,
    const int* __restrict__ idx, u16* __restrict__ Kc, u16* __restrict__ Vt) {
  const int bid = blockIdx.x;
  const int t = threadIdx.x;
  if (bid < 1024) {
    __shared__ u16 tile[64][65];
    const int posT = bid & 31, dmT = (bid >> 5) & 15, b = bid >> 9;
    const int r = t >> 2, cg = (t & 3) * 16;
    const int srow = idx[b * SEQ + posT * 64 + r];
    const u16* src = Vin + ((size_t)b * SEQ + srow) * DM + dmT * 64 + cg;
    u16 v[16] __attribute__((aligned(16)));
    *(uint4*)&v[0] = *(const uint4*)src;
    *(uint4*)&v[8] = *(const uint4*)(src + 8);
#pragma unroll
    for (int j = 0; j < 16; ++j) tile[r][cg + j] = v[j];
    __syncthreads();
    u16 u[16] __attribute__((aligned(16)));
#pragma unroll
    for (int j = 0; j < 16; ++j) u[j] = tile[cg + j][r];
    u16* dst = Vt + ((size_t)b * DM + dmT * 64 + r) * SEQ + posT * 64 + cg;
    *(uint4*)&dst[0] = *(uint4*)&u[0];
    *(uint4*)&dst[8] = *(uint4*)&u[8];
  } else {  // K gather: Kc[b][p][:] = Kin[b][idx[p]][:]
    const int kb = bid - 1024;          // 0..127
    const int b = kb >> 6, rg = kb & 63;
    const int r = rg * 32 + (t >> 3), chunk = t & 7;
    const int srow = idx[b * SEQ + r];
    const uint4* src = (const uint4*)(Kin + ((size_t)b * SEQ + srow) * DM) + chunk;
    uint4* dst = (uint4*)(Kc + ((size_t)b * SEQ + r) * DM) + chunk;
#pragma unroll
    for (int j = 0; j < 16; ++j) dst[j * 8] = src[j * 8];
  }
}

// ---------------------------------------------------------------------------
// GEMM: C[M][N] = A[M][K] @ Bt[N][K]^T, bf16 in, f32 accum. 128x128, BK=64.
// ---------------------------------------------------------------------------
template <int OUT_F32>
__device__ __forceinline__ void gemm128_body(
    const u16* __restrict__ A, const u16* __restrict__ Bt, void* __restrict__ Cv,
    int M, int N, int K, int bx, int by) {
  __shared__ u16 As[128 * 64];
  __shared__ u16 Bs[128 * 64];
  const int m0 = by * 128, n0 = bx * 128;
  const int t = threadIdx.x, w = t >> 6, l = t & 63;
  const int wr = w >> 1, wc = w & 1;
  const int frow = l & 15, fk8 = (l >> 4) * 8;
  f32x4 acc[4][4] = {};

  for (int k0 = 0; k0 < K; k0 += 64) {
#pragma unroll
    for (int i = 0; i < 4; ++i) {
      const int base = (i * 4 + w) * 1024;
      const int e = (base >> 1) + l * 8;
      const int row = e >> 6, col = e & 63;
      async_g2l16(A + (size_t)(m0 + row) * K + k0 + col, (char*)As + base);
      async_g2l16(Bt + (size_t)(n0 + row) * K + k0 + col, (char*)Bs + base);
    }
    __syncthreads();
#pragma unroll
    for (int kk = 0; kk < 2; ++kk) {
      short8 af[4], bf[4];
#pragma unroll
      for (int mi = 0; mi < 4; ++mi)
        af[mi] = *(const short8*)&As[(wr * 64 + mi * 16 + frow) * 64 + kk * 32 + fk8];
#pragma unroll
      for (int ni = 0; ni < 4; ++ni)
        bf[ni] = *(const short8*)&Bs[(wc * 64 + ni * 16 + frow) * 64 + kk * 32 + fk8];
#pragma unroll
      for (int mi = 0; mi < 4; ++mi)
#pragma unroll
        for (int ni = 0; ni < 4; ++ni)
          acc[mi][ni] = MFMA(af[mi], bf[ni], acc[mi][ni]);
    }
    __syncthreads();
  }

  const int crb = (l >> 4) * 4;
  for (int mi = 0; mi < 4; ++mi)
    for (int ni = 0; ni < 4; ++ni)
#pragma unroll
      for (int r = 0; r < 4; ++r) {
        const int row = m0 + wr * 64 + mi * 16 + crb + r;
        const int col = n0 + wc * 64 + ni * 16 + frow;
        if (OUT_F32) ((float*)Cv)[(size_t)row * N + col] = acc[mi][ni][r];
        else         ((u16*)Cv)[(size_t)row * N + col] = f2bf(acc[mi][ni][r]);
      }
}

// XCD-aware bijective swizzle for 256-block (8x32) grids
__device__ __forceinline__ void swz256(int& bx, int& by) {
  const int lin = by * 8 + bx;
  const int s = (lin & 7) * 32 + (lin >> 3);
  bx = s & 7; by = s >> 3;
}

__global__ __launch_bounds__(256) void gemm_qkv(
    const u16* __restrict__ xin, const u16* __restrict__ wt, u16* __restrict__ out) {
  const int z = blockIdx.z;
  int bx = blockIdx.x, by = blockIdx.y;
  swz256(bx, by);
  gemm128_body<0>(xin + (size_t)z * NB * SEQ * DM, wt + (size_t)z * DM * DM,
                  out + (size_t)z * NB * SEQ * DM,
                  NB * SEQ, DM, DM, bx, by);
}

__global__ __launch_bounds__(256) void gemm_out(
    const u16* __restrict__ A, const u16* __restrict__ Bt, float* __restrict__ C) {
  int bx = blockIdx.x, by = blockIdx.y;
  swz256(bx, by);
  gemm128_body<1>(A, Bt, C, NB * SEQ, DM, DM, bx, by);
}

// ---------------------------------------------------------------------------
// Flash attention v4: compacted K/V both pre-gathered (no idx chain in-loop).
// 512 thr (8 waves), 128 q/block (16/wave), KV tile 64, triple-buffered
// 2-deep prefetch with counted vmcnt(2) + raw s_barrier (drain only at tail).
// XCD swizzle: each XCD owns 4 heads of one batch (K/V L2-resident).
// ---------------------------------------------------------------------------
__global__ __launch_bounds__(512) void attn(
    const u16* __restrict__ Q, const u16* __restrict__ Kc,
    const u16* __restrict__ Vtc, const int* __restrict__ nkv,
    u16* __restrict__ O) {
  __shared__ uint4 ldsv[65536 / 16];
  char* lds = (char*)ldsv;       // [0,24K) K x3 | [24K,48K) V x3 | [48K,64K) P x8

  const int bid = blockIdx.x;
  const int swz = (bid & 7) * 64 + (bid >> 3);   // 512 blocks, bijective
  const int qt = swz & 15, h = (swz >> 4) & 15, b = swz >> 8;
  const int t = threadIdx.x, w = t >> 6, l = t & 63;
  const int frow = l & 15, fk8 = (l >> 4) * 8, crb = (l >> 4) * 4;
  const size_t tok0 = (size_t)b * SEQ;
  const int q0 = qt * 128 + w * 16;
  const int hc = h * DKH;
  char* PW = lds + 49152 + w * 2048;

  const int nk = nkv[b];
  const int nt = (nk + 63) >> 6;

  // staging: per wave 1 K + 1 V g2l16 (rows w*8 .. w*8+7), pre-swizzled source
  const int T0 = w * 1024 + l * 16;
  const int r0 = T0 >> 7;
  const int c0 = (T0 & 127) ^ ((r0 & 7) << 4);
  const u16* Kg = Kc + tok0 * DM + hc;
  const u16* Vg = Vtc + ((size_t)b * DM + hc) * SEQ;

  short8 qf[2];
#pragma unroll
  for (int ks = 0; ks < 2; ++ks)
    qf[ks] = *(const short8*)(Q + (tok0 + q0 + frow) * DM + hc + ks * 32 + fk8);

  const short ONE = 0x3F80;
  const short8 ONES = {ONE, ONE, ONE, ONE, ONE, ONE, ONE, ONE};

  f32x4 o[4] = {};
  f32x4 ol = {};
  float negm[4] = {-8.f, -8.f, -8.f, -8.f};

  char* kb0 = lds;          char* kb1 = lds + 8192;   char* kb2 = lds + 16384;
  char* vb0 = lds + 24576;  char* vb1 = lds + 32768;  char* vb2 = lds + 40960;

#define STAGE(tile, kd, vd)                                                    \
  do {                                                                         \
    const int kv_ = (tile) * 64;                                               \
    async_g2l16((const char*)(Kg + (size_t)(kv_ + r0) * DM) + c0, (kd) + w * 1024); \
    async_g2l16((const char*)(Vg + (size_t)r0 * SEQ + kv_) + c0, (vd) + w * 1024);  \
  } while (0)

  if (nt > 0) STAGE(0, kb0, vb0);
  if (nt > 1) STAGE(1, kb1, vb1);

  for (int it = 0; it < nt; ++it) {
    if (it + 1 < nt) { asm volatile("s_waitcnt vmcnt(2)" ::: "memory"); }
    else             { asm volatile("s_waitcnt vmcnt(0)" ::: "memory"); }
    __builtin_amdgcn_s_barrier();
    __builtin_amdgcn_sched_barrier(0);
    if (it + 2 < nt) STAGE(it + 2, kb2, vb2);

    const int kv0 = it * 64;
    const char* Kt = kb0;
    const char* Vt = vb0;

    // ---- QK^T + scale + negm fold ----
    f32x4 s[4];
#pragma unroll
    for (int n = 0; n < 4; ++n) {
      short8 kf0 = lds_sw(Kt, n * 16 + frow, fk8 * 2);
      short8 kf1 = lds_sw(Kt, n * 16 + frow, 64 + fk8 * 2);
      f32x4 a = {};
      a = MFMA(qf[0], kf0, a);
      a = MFMA(qf[1], kf1, a);
      s[n] = a;
    }
#pragma unroll
    for (int n = 0; n < 4; ++n)
#pragma unroll
      for (int r = 0; r < 4; ++r)
        s[n][r] = __builtin_fmaf(s[n][r], SCL, negm[r]);

    // ---- last-tile pad kill ----
    if (it == nt - 1) {
#pragma unroll
      for (int n = 0; n < 4; ++n) {
        const bool valid = (kv0 + n * 16 + frow) < nk;
#pragma unroll
        for (int r = 0; r < 4; ++r)
          s[n][r] = valid ? s[n][r] : -1e30f;
      }
    }

    // ---- defer-max (THR=8) ----
    float lm = fmaxf(fmaxf(fmaxf(s[0][0], s[0][1]), fmaxf(s[0][2], s[0][3])),
                     fmaxf(fmaxf(s[1][0], s[1][1]), fmaxf(s[1][2], s[1][3])));
    lm = fmaxf(lm, fmaxf(fmaxf(s[2][0], s[2][1]), fmaxf(s[2][2], s[2][3])));
    lm = fmaxf(lm, fmaxf(fmaxf(s[3][0], s[3][1]), fmaxf(s[3][2], s[3][3])));
    if (__any(lm > 8.0f)) {
#pragma unroll
      for (int r = 0; r < 4; ++r) {
        float mx = fmaxf(fmaxf(s[0][r], s[1][r]), fmaxf(s[2][r], s[3][r]));
        mx = fmaxf(mx, __shfl_xor(mx, 1));
        mx = fmaxf(mx, __shfl_xor(mx, 2));
        mx = fmaxf(mx, __shfl_xor(mx, 4));
        mx = fmaxf(mx, __shfl_xor(mx, 8));
        const float d = fmaxf(mx, 0.f);
        const float al = exp2f(-d);
        negm[r] -= d;
        ol[r] *= al;
#pragma unroll
        for (int dd = 0; dd < 4; ++dd) o[dd][r] *= al;
#pragma unroll
        for (int n = 0; n < 4; ++n) s[n][r] -= d;
      }
    }

    // ---- exp + truncated bf16 P write (swizzled) ----
#pragma unroll
    for (int n = 0; n < 4; ++n)
#pragma unroll
      for (int r = 0; r < 4; ++r) {
        const float p = exp2f(s[n][r]);
        *(u16*)(PW + (crb + r) * 128 +
                ((n * 32 + frow * 2) ^ (((crb + r) & 7) << 4))) =
            (u16)(__builtin_bit_cast(uint32_t, p) >> 16);
      }
    asm volatile("s_waitcnt lgkmcnt(0)" ::: "memory");
    __builtin_amdgcn_sched_barrier(0);

    // ---- PV + row-sum via ones-MFMA ----
    short8 pa0 = lds_sw(PW, frow, fk8 * 2);
    short8 pa1 = lds_sw(PW, frow, 64 + fk8 * 2);
    ol = MFMA(pa1, ONES, MFMA(pa0, ONES, ol));
#pragma unroll
    for (int d = 0; d < 4; ++d) {
      short8 vf0 = lds_sw(Vt, d * 16 + frow, fk8 * 2);
      short8 vf1 = lds_sw(Vt, d * 16 + frow, 64 + fk8 * 2);
      o[d] = MFMA(pa1, vf1, MFMA(pa0, vf0, o[d]));
    }

    // rotate buffers
    char* tk = kb0; kb0 = kb1; kb1 = kb2; kb2 = tk;
    char* tv = vb0; vb0 = vb1; vb1 = vb2; vb2 = tv;
  }
#undef STAGE

  // ---- epilogue ----
#pragma unroll
  for (int r = 0; r < 4; ++r) {
    const float den = ol[r];
    const float inv = den > 0.f ? 1.f / den : 0.f;
#pragma unroll
    for (int d = 0; d < 4; ++d)
      O[(tok0 + q0 + crb + r) * DM + hc + d * 16 + frow] = f2bf(o[d][r] * inv);
  }
}

// ---------------------------------------------------------------------------
extern "C" void kernel_launch(void* const* d_in, const int* in_sizes, int n_in,
                              void* d_out, int out_size, void* d_ws, size_t ws_size,
                              hipStream_t stream) {
  const float* query = (const float*)d_in[0];
  const float* key_  = (const float*)d_in[1];
  const float* value = (const float*)d_in[2];
  const int* mask    = (const int*)d_in[3];
  const float* wq = (const float*)d_in[4];
  const float* wk = (const float*)d_in[5];
  const float* wv = (const float*)d_in[6];
  const float* wo = (const float*)d_in[7];
  float* out = (float*)d_out;
  char* ws = (char*)d_ws;

  // ws layout (bytes):
  // [0,6M)    Wt_QKV (bf16, transposed)   [6M,8M)  Wt_O
  // [8M,32M)  xin (bf16 q|k|v) — live until gemm_qkv; AFTER that:
  //   [8M,16M)  Vtc   [16M,24M) attn_o   [24M,32M) Kc (compacted K)
  // [32M,56M) Q|K|V projections (bf16)
  // [56M,+16K) idx  [+16K,+8) nkv   (disjoint; r4 lesson)
  u16* wt_qkv = (u16*)(ws);
  u16* wt_o   = (u16*)(ws + (6u << 20));
  u16* xin    = (u16*)(ws + (8u << 20));
  u16* vtc    = (u16*)(ws + (8u << 20));
  u16* attn_o = (u16*)(ws + (16u << 20));
  u16* kc     = (u16*)(ws + (24u << 20));
  u16* qkv    = (u16*)(ws + (32u << 20));
  int* idx    = (int*)(ws + (56u << 20));
  int* nkv    = (int*)(ws + (56u << 20) + 16384);

  prep<<<dim3(7170), 256, 0, stream>>>(
      query, key_, value, mask, wq, wk, wv, wo, xin, wt_qkv, wt_o, idx, nkv);

  gemm_qkv<<<dim3(DM / 128, (NB * SEQ) / 128, 3), 256, 0, stream>>>(
      xin, wt_qkv, qkv);

  kvprep<<<dim3(1152), 256, 0, stream>>>(
      qkv + (size_t)NB * SEQ * DM, qkv + (size_t)2 * NB * SEQ * DM, idx, kc, vtc);

  attn<<<dim3(NB * NH * (SEQ / 128)), 512, 0, stream>>>(
      qkv, kc, vtc, nkv, attn_o);

  gemm_out<<<dim3(DM / 128, (NB * SEQ) / 128), 256, 0, stream>>>(
      attn_o, wt_o, out);
}

// Round 7
// 214.473 us; speedup vs baseline: 1.5135x; 1.0403x over previous
//
#include <hip/hip_runtime.h>
#include <hip/hip_bf16.h>
#include <stdint.h>

#define DM  1024
#define SEQ 2048
#define NB  2
#define NH  16
#define DKH 64
#define SCL 0.18033688f  // (1/sqrt(64)) * log2(e)  — softmax in exp2 domain

typedef unsigned short u16;
typedef __attribute__((ext_vector_type(8))) short short8;
typedef __attribute__((ext_vector_type(4))) float f32x4;

#define MFMA(a,b,c) __builtin_amdgcn_mfma_f32_16x16x32_bf16((a),(b),(c),0,0,0)

__device__ __forceinline__ void async_g2l16(const void* g, void* l) {
  __builtin_amdgcn_global_load_lds(
      (const __attribute__((address_space(1))) uint32_t*)g,
      (__attribute__((address_space(3))) uint32_t*)l, 16, 0, 0);
}

__device__ __forceinline__ u16 f2bf(float f) {
  uint32_t u = __builtin_bit_cast(uint32_t, f);
  u += 0x7fffu + ((u >> 16) & 1u);
  return (u16)(u >> 16);
}

// swizzled LDS read: logical (row, col-byte) over 128B rows, XOR bits 4-6
__device__ __forceinline__ short8 lds_sw(const char* base, int row, int cb) {
  return *(const short8*)(base + row * 128 + (cb ^ ((row & 7) << 4)));
}

// ---------------------------------------------------------------------------
// prep: fused {weight transpose+convert | q/k/v f32->bf16 convert | mask scan}
// blocks [0,1024): transpose; [1024,7168): conv; [7168,7170): mask scan.
// ---------------------------------------------------------------------------
__global__ __launch_bounds__(256) void prep(
    const float* __restrict__ query, const float* __restrict__ key_,
    const float* __restrict__ value, const int* __restrict__ mask,
    const float* __restrict__ w0, const float* __restrict__ w1,
    const float* __restrict__ w2, const float* __restrict__ w3,
    u16* __restrict__ xin, u16* __restrict__ wt_qkv, u16* __restrict__ wt_o,
    int* __restrict__ idx, int* __restrict__ nkv) {
  __shared__ char shm[8320];
  const int bid = blockIdx.x;
  const int t = threadIdx.x;

  if (bid < 1024) {  // ---- weight transpose: Wt[n][k] = bf16(W[k][n]) ----
    u16 (*tile)[65] = (u16(*)[65])shm;
    const int z = bid >> 8, rem = bid & 255;
    const float* W = (z == 0) ? w0 : (z == 1) ? w1 : (z == 2) ? w2 : w3;
    u16* O = (z < 3) ? (wt_qkv + (size_t)z * DM * DM) : wt_o;
    const int k0 = (rem & 15) * 64, n0 = (rem >> 4) * 64;
    const int r = t >> 2, cg = (t & 3) * 16;
    const float* src = W + (size_t)(k0 + r) * DM + n0 + cg;
#pragma unroll
    for (int j = 0; j < 4; ++j) {
      const float4 a = ((const float4*)src)[j];
      tile[r][cg + j * 4 + 0] = f2bf(a.x);
      tile[r][cg + j * 4 + 1] = f2bf(a.y);
      tile[r][cg + j * 4 + 2] = f2bf(a.z);
      tile[r][cg + j * 4 + 3] = f2bf(a.w);
    }
    __syncthreads();
    u16 u[16] __attribute__((aligned(16)));
#pragma unroll
    for (int j = 0; j < 16; ++j) u[j] = tile[cg + j][r];
    u16* dst = O + (size_t)(n0 + r) * DM + k0 + cg;
    *(uint4*)&dst[0] = *(uint4*)&u[0];
    *(uint4*)&dst[8] = *(uint4*)&u[8];
  } else if (bid < 7168) {  // ---- f32 -> bf16 convert ----
    const int cb = bid - 1024;
    const int z = cb >> 11;
    const float* A = (z == 0) ? query : (z == 1) ? key_ : value;
    u16* O = xin + (size_t)z * NB * SEQ * DM;
    const size_t i = (size_t)(cb & 2047) * 256 + t;
    const float4 a = ((const float4*)A)[i * 2];
    const float4 b = ((const float4*)A)[i * 2 + 1];
    u16 v[8] __attribute__((aligned(16)));
    v[0] = f2bf(a.x); v[1] = f2bf(a.y); v[2] = f2bf(a.z); v[3] = f2bf(a.w);
    v[4] = f2bf(b.x); v[5] = f2bf(b.y); v[6] = f2bf(b.z); v[7] = f2bf(b.w);
    *(uint4*)(O + i * 8) = *(uint4*)v;
  } else {  // ---- mask compaction scan ----
    int* cnt = (int*)shm;
    const int b = bid - 7168;
    const int* mp = mask + b * SEQ + t * 8;
    int m[8], c = 0;
#pragma unroll
    for (int j = 0; j < 8; ++j) { m[j] = mp[j]; c += (m[j] == 0); }
    cnt[t] = c;
    __syncthreads();
    for (int off = 1; off < 256; off <<= 1) {
      int v = 0;
      if (t >= off) v = cnt[t - off];
      __syncthreads();
      if (t >= off) cnt[t] += v;
      __syncthreads();
    }
    int base = cnt[t] - c;
    int* ip = idx + b * SEQ;
#pragma unroll
    for (int j = 0; j < 8; ++j)
      if (m[j] == 0) ip[base++] = t * 8 + j;
    const int total = cnt[255];
    if (t == 0) nkv[b] = total;
    for (int p = total + t; p < SEQ; p += 256) ip[p] = 0;
  }
}

// ---------------------------------------------------------------------------
// kvprep: fused {V gather-transpose | K gather}.
// blocks [0,1024): Vt[b][dm][pos]=V[b][idx[pos]][dm]; [1024,1152): K gather.
// ---------------------------------------------------------------------------
__global__ __launch_bounds__(256) void kvprep(
    const u16* __restrict__ Kin, const u16* __restrict__ Vin,
    const int* __restrict__ idx, u16* __restrict__ Kc, u16* __restrict__ Vt) {
  const int bid = blockIdx.x;
  const int t = threadIdx.x;
  if (bid < 1024) {
    __shared__ u16 tile[64][65];
    const int posT = bid & 31, dmT = (bid >> 5) & 15, b = bid >> 9;
    const int r = t >> 2, cg = (t & 3) * 16;
    const int srow = idx[b * SEQ + posT * 64 + r];
    const u16* src = Vin + ((size_t)b * SEQ + srow) * DM + dmT * 64 + cg;
    u16 v[16] __attribute__((aligned(16)));
    *(uint4*)&v[0] = *(const uint4*)src;
    *(uint4*)&v[8] = *(const uint4*)(src + 8);
#pragma unroll
    for (int j = 0; j < 16; ++j) tile[r][cg + j] = v[j];
    __syncthreads();
    u16 u[16] __attribute__((aligned(16)));
#pragma unroll
    for (int j = 0; j < 16; ++j) u[j] = tile[cg + j][r];
    u16* dst = Vt + ((size_t)b * DM + dmT * 64 + r) * SEQ + posT * 64 + cg;
    *(uint4*)&dst[0] = *(uint4*)&u[0];
    *(uint4*)&dst[8] = *(uint4*)&u[8];
  } else {  // K gather: Kc[b][p][:] = Kin[b][idx[p]][:]
    const int kb = bid - 1024;          // 0..127
    const int b = kb >> 6, rg = kb & 63;
    const int r = rg * 32 + (t >> 3), chunk = t & 7;
    const int srow = idx[b * SEQ + r];
    const uint4* src = (const uint4*)(Kin + ((size_t)b * SEQ + srow) * DM) + chunk;
    uint4* dst = (uint4*)(Kc + ((size_t)b * SEQ + r) * DM) + chunk;
#pragma unroll
    for (int j = 0; j < 16; ++j) dst[j * 8] = src[j * 8];
  }
}

// ---------------------------------------------------------------------------
// GEMM v2: C[M][N] = A[M][K] @ Bt[N][K]^T, bf16 in, f32 accum. 128x128, BK=64.
// Proper 2-phase: double-buffered LDS, STAGE(t+1) issued BEFORE compute(t),
// one (compiler-emitted) vmcnt(0)+barrier per K-step. T2 XOR-swizzle on both
// tiles via pre-swizzled global sources. setprio(1) around the MFMA cluster.
// ---------------------------------------------------------------------------
template <int OUT_F32>
__device__ __forceinline__ void gemm128_body(
    const u16* __restrict__ A, const u16* __restrict__ Bt, void* __restrict__ Cv,
    int M, int N, int K, int bx, int by) {
  __shared__ u16 As[2][128 * 64];
  __shared__ u16 Bs[2][128 * 64];
  const int m0 = by * 128, n0 = bx * 128;
  const int t = threadIdx.x, w = t >> 6, l = t & 63;
  const int wr = w >> 1, wc = w & 1;
  const int frow = l & 15, fk8 = (l >> 4) * 8;
  f32x4 acc[4][4] = {};

  // staging geometry: 4 chunks/thread/tensor; chunk i covers LDS bytes
  // T=(i*4+w)*1024 + l*16 of the 16KB tile. Linear LDS dest + inverse-swizzled
  // global source col (rule #21) -> swizzled layout readable via lds_sw.
  int srow[4], scb[4];
#pragma unroll
  for (int i = 0; i < 4; ++i) {
    const int T = (i * 4 + w) * 1024 + l * 16;
    srow[i] = T >> 7;
    scb[i] = (T & 127) ^ ((srow[i] & 7) << 4);
  }

#define GSTAGE(buf, k0)                                                        \
  do {                                                                         \
    _Pragma("unroll")                                                          \
    for (int i = 0; i < 4; ++i) {                                              \
      const int T = (i * 4 + w) * 1024 + l * 16;                               \
      async_g2l16((const char*)(A + (size_t)(m0 + srow[i]) * K + (k0)) + scb[i],  \
                  (char*)As[buf] + T);                                         \
      async_g2l16((const char*)(Bt + (size_t)(n0 + srow[i]) * K + (k0)) + scb[i], \
                  (char*)Bs[buf] + T);                                         \
    }                                                                          \
  } while (0)

  const int nkstep = K >> 6;
  GSTAGE(0, 0);
  __syncthreads();                       // compiler drains vmcnt(0) here

  int cur = 0;
  for (int ks = 0; ks < nkstep; ++ks) {
    if (ks + 1 < nkstep) GSTAGE(cur ^ 1, (ks + 1) * 64);  // fly under compute
    __builtin_amdgcn_s_setprio(1);
#pragma unroll
    for (int kk = 0; kk < 2; ++kk) {
      short8 af[4], bf[4];
#pragma unroll
      for (int mi = 0; mi < 4; ++mi)
        af[mi] = lds_sw((const char*)As[cur], wr * 64 + mi * 16 + frow,
                        kk * 64 + fk8 * 2);
#pragma unroll
      for (int ni = 0; ni < 4; ++ni)
        bf[ni] = lds_sw((const char*)Bs[cur], wc * 64 + ni * 16 + frow,
                        kk * 64 + fk8 * 2);
#pragma unroll
      for (int mi = 0; mi < 4; ++mi)
#pragma unroll
        for (int ni = 0; ni < 4; ++ni)
          acc[mi][ni] = MFMA(af[mi], bf[ni], acc[mi][ni]);
    }
    __builtin_amdgcn_s_setprio(0);
    __syncthreads();                     // drains next tile's stage + lds reads
    cur ^= 1;
  }
#undef GSTAGE

  const int crb = (l >> 4) * 4;
  for (int mi = 0; mi < 4; ++mi)
    for (int ni = 0; ni < 4; ++ni)
#pragma unroll
      for (int r = 0; r < 4; ++r) {
        const int row = m0 + wr * 64 + mi * 16 + crb + r;
        const int col = n0 + wc * 64 + ni * 16 + frow;
        if (OUT_F32) ((float*)Cv)[(size_t)row * N + col] = acc[mi][ni][r];
        else         ((u16*)Cv)[(size_t)row * N + col] = f2bf(acc[mi][ni][r]);
      }
}

// XCD-aware bijective swizzle for 256-block (8x32) grids
__device__ __forceinline__ void swz256(int& bx, int& by) {
  const int lin = by * 8 + bx;
  const int s = (lin & 7) * 32 + (lin >> 3);
  bx = s & 7; by = s >> 3;
}

__global__ __launch_bounds__(256) void gemm_qkv(
    const u16* __restrict__ xin, const u16* __restrict__ wt, u16* __restrict__ out) {
  const int z = blockIdx.z;
  int bx = blockIdx.x, by = blockIdx.y;
  swz256(bx, by);
  gemm128_body<0>(xin + (size_t)z * NB * SEQ * DM, wt + (size_t)z * DM * DM,
                  out + (size_t)z * NB * SEQ * DM,
                  NB * SEQ, DM, DM, bx, by);
}

__global__ __launch_bounds__(256) void gemm_out(
    const u16* __restrict__ A, const u16* __restrict__ Bt, float* __restrict__ C) {
  int bx = blockIdx.x, by = blockIdx.y;
  swz256(bx, by);
  gemm128_body<1>(A, Bt, C, NB * SEQ, DM, DM, bx, by);
}

// ---------------------------------------------------------------------------
// Flash attention v4 (unchanged from round 6): compacted K/V pre-gathered,
// 512 thr (8 waves), 128 q/block, KV tile 64, triple-buffered 2-deep prefetch
// with counted vmcnt(2) + raw s_barrier. XCD swizzle for K/V L2 residency.
// ---------------------------------------------------------------------------
__global__ __launch_bounds__(512) void attn(
    const u16* __restrict__ Q, const u16* __restrict__ Kc,
    const u16* __restrict__ Vtc, const int* __restrict__ nkv,
    u16* __restrict__ O) {
  __shared__ uint4 ldsv[65536 / 16];
  char* lds = (char*)ldsv;       // [0,24K) K x3 | [24K,48K) V x3 | [48K,64K) P x8

  const int bid = blockIdx.x;
  const int swz = (bid & 7) * 64 + (bid >> 3);   // 512 blocks, bijective
  const int qt = swz & 15, h = (swz >> 4) & 15, b = swz >> 8;
  const int t = threadIdx.x, w = t >> 6, l = t & 63;
  const int frow = l & 15, fk8 = (l >> 4) * 8, crb = (l >> 4) * 4;
  const size_t tok0 = (size_t)b * SEQ;
  const int q0 = qt * 128 + w * 16;
  const int hc = h * DKH;
  char* PW = lds + 49152 + w * 2048;

  const int nk = nkv[b];
  const int nt = (nk + 63) >> 6;

  const int T0 = w * 1024 + l * 16;
  const int r0 = T0 >> 7;
  const int c0 = (T0 & 127) ^ ((r0 & 7) << 4);
  const u16* Kg = Kc + tok0 * DM + hc;
  const u16* Vg = Vtc + ((size_t)b * DM + hc) * SEQ;

  short8 qf[2];
#pragma unroll
  for (int ks = 0; ks < 2; ++ks)
    qf[ks] = *(const short8*)(Q + (tok0 + q0 + frow) * DM + hc + ks * 32 + fk8);

  const short ONE = 0x3F80;
  const short8 ONES = {ONE, ONE, ONE, ONE, ONE, ONE, ONE, ONE};

  f32x4 o[4] = {};
  f32x4 ol = {};
  float negm[4] = {-8.f, -8.f, -8.f, -8.f};

  char* kb0 = lds;          char* kb1 = lds + 8192;   char* kb2 = lds + 16384;
  char* vb0 = lds + 24576;  char* vb1 = lds + 32768;  char* vb2 = lds + 40960;

#define STAGE(tile, kd, vd)                                                    \
  do {                                                                         \
    const int kv_ = (tile) * 64;                                               \
    async_g2l16((const char*)(Kg + (size_t)(kv_ + r0) * DM) + c0, (kd) + w * 1024); \
    async_g2l16((const char*)(Vg + (size_t)r0 * SEQ + kv_) + c0, (vd) + w * 1024);  \
  } while (0)

  if (nt > 0) STAGE(0, kb0, vb0);
  if (nt > 1) STAGE(1, kb1, vb1);

  for (int it = 0; it < nt; ++it) {
    if (it + 1 < nt) { asm volatile("s_waitcnt vmcnt(2)" ::: "memory"); }
    else             { asm volatile("s_waitcnt vmcnt(0)" ::: "memory"); }
    __builtin_amdgcn_s_barrier();
    __builtin_amdgcn_sched_barrier(0);
    if (it + 2 < nt) STAGE(it + 2, kb2, vb2);

    const int kv0 = it * 64;
    const char* Kt = kb0;
    const char* Vt = vb0;

    // ---- QK^T + scale + negm fold ----
    f32x4 s[4];
#pragma unroll
    for (int n = 0; n < 4; ++n) {
      short8 kf0 = lds_sw(Kt, n * 16 + frow, fk8 * 2);
      short8 kf1 = lds_sw(Kt, n * 16 + frow, 64 + fk8 * 2);
      f32x4 a = {};
      a = MFMA(qf[0], kf0, a);
      a = MFMA(qf[1], kf1, a);
      s[n] = a;
    }
#pragma unroll
    for (int n = 0; n < 4; ++n)
#pragma unroll
      for (int r = 0; r < 4; ++r)
        s[n][r] = __builtin_fmaf(s[n][r], SCL, negm[r]);

    // ---- last-tile pad kill ----
    if (it == nt - 1) {
#pragma unroll
      for (int n = 0; n < 4; ++n) {
        const bool valid = (kv0 + n * 16 + frow) < nk;
#pragma unroll
        for (int r = 0; r < 4; ++r)
          s[n][r] = valid ? s[n][r] : -1e30f;
      }
    }

    // ---- defer-max (THR=8) ----
    float lm = fmaxf(fmaxf(fmaxf(s[0][0], s[0][1]), fmaxf(s[0][2], s[0][3])),
                     fmaxf(fmaxf(s[1][0], s[1][1]), fmaxf(s[1][2], s[1][3])));
    lm = fmaxf(lm, fmaxf(fmaxf(s[2][0], s[2][1]), fmaxf(s[2][2], s[2][3])));
    lm = fmaxf(lm, fmaxf(fmaxf(s[3][0], s[3][1]), fmaxf(s[3][2], s[3][3])));
    if (__any(lm > 8.0f)) {
#pragma unroll
      for (int r = 0; r < 4; ++r) {
        float mx = fmaxf(fmaxf(s[0][r], s[1][r]), fmaxf(s[2][r], s[3][r]));
        mx = fmaxf(mx, __shfl_xor(mx, 1));
        mx = fmaxf(mx, __shfl_xor(mx, 2));
        mx = fmaxf(mx, __shfl_xor(mx, 4));
        mx = fmaxf(mx, __shfl_xor(mx, 8));
        const float d = fmaxf(mx, 0.f);
        const float al = exp2f(-d);
        negm[r] -= d;
        ol[r] *= al;
#pragma unroll
        for (int dd = 0; dd < 4; ++dd) o[dd][r] *= al;
#pragma unroll
        for (int n = 0; n < 4; ++n) s[n][r] -= d;
      }
    }

    // ---- exp + truncated bf16 P write (swizzled) ----
#pragma unroll
    for (int n = 0; n < 4; ++n)
#pragma unroll
      for (int r = 0; r < 4; ++r) {
        const float p = exp2f(s[n][r]);
        *(u16*)(PW + (crb + r) * 128 +
                ((n * 32 + frow * 2) ^ (((crb + r) & 7) << 4))) =
            (u16)(__builtin_bit_cast(uint32_t, p) >> 16);
      }
    asm volatile("s_waitcnt lgkmcnt(0)" ::: "memory");
    __builtin_amdgcn_sched_barrier(0);

    // ---- PV + row-sum via ones-MFMA ----
    short8 pa0 = lds_sw(PW, frow, fk8 * 2);
    short8 pa1 = lds_sw(PW, frow, 64 + fk8 * 2);
    ol = MFMA(pa1, ONES, MFMA(pa0, ONES, ol));
#pragma unroll
    for (int d = 0; d < 4; ++d) {
      short8 vf0 = lds_sw(Vt, d * 16 + frow, fk8 * 2);
      short8 vf1 = lds_sw(Vt, d * 16 + frow, 64 + fk8 * 2);
      o[d] = MFMA(pa1, vf1, MFMA(pa0, vf0, o[d]));
    }

    // rotate buffers
    char* tk = kb0; kb0 = kb1; kb1 = kb2; kb2 = tk;
    char* tv = vb0; vb0 = vb1; vb1 = vb2; vb2 = tv;
  }
#undef STAGE

  // ---- epilogue ----
#pragma unroll
  for (int r = 0; r < 4; ++r) {
    const float den = ol[r];
    const float inv = den > 0.f ? 1.f / den : 0.f;
#pragma unroll
    for (int d = 0; d < 4; ++d)
      O[(tok0 + q0 + crb + r) * DM + hc + d * 16 + frow] = f2bf(o[d][r] * inv);
  }
}

// ---------------------------------------------------------------------------
extern "C" void kernel_launch(void* const* d_in, const int* in_sizes, int n_in,
                              void* d_out, int out_size, void* d_ws, size_t ws_size,
                              hipStream_t stream) {
  const float* query = (const float*)d_in[0];
  const float* key_  = (const float*)d_in[1];
  const float* value = (const float*)d_in[2];
  const int* mask    = (const int*)d_in[3];
  const float* wq = (const float*)d_in[4];
  const float* wk = (const float*)d_in[5];
  const float* wv = (const float*)d_in[6];
  const float* wo = (const float*)d_in[7];
  float* out = (float*)d_out;
  char* ws = (char*)d_ws;

  // ws layout (bytes):
  // [0,6M)    Wt_QKV (bf16, transposed)   [6M,8M)  Wt_O
  // [8M,32M)  xin (bf16 q|k|v) — live until gemm_qkv; AFTER that:
  //   [8M,16M)  Vtc   [16M,24M) attn_o   [24M,32M) Kc (compacted K)
  // [32M,56M) Q|K|V projections (bf16)
  // [56M,+16K) idx  [+16K,+8) nkv   (disjoint; r4 lesson)
  u16* wt_qkv = (u16*)(ws);
  u16* wt_o   = (u16*)(ws + (6u << 20));
  u16* xin    = (u16*)(ws + (8u << 20));
  u16* vtc    = (u16*)(ws + (8u << 20));
  u16* attn_o = (u16*)(ws + (16u << 20));
  u16* kc     = (u16*)(ws + (24u << 20));
  u16* qkv    = (u16*)(ws + (32u << 20));
  int* idx    = (int*)(ws + (56u << 20));
  int* nkv    = (int*)(ws + (56u << 20) + 16384);

  prep<<<dim3(7170), 256, 0, stream>>>(
      query, key_, value, mask, wq, wk, wv, wo, xin, wt_qkv, wt_o, idx, nkv);

  gemm_qkv<<<dim3(DM / 128, (NB * SEQ) / 128, 3), 256, 0, stream>>>(
      xin, wt_qkv, qkv);

  kvprep<<<dim3(1152), 256, 0, stream>>>(
      qkv + (size_t)NB * SEQ * DM, qkv + (size_t)2 * NB * SEQ * DM, idx, kc, vtc);

  attn<<<dim3(NB * NH * (SEQ / 128)), 512, 0, stream>>>(
      qkv, kc, vtc, nkv, attn_o);

  gemm_out<<<dim3(DM / 128, (NB * SEQ) / 128), 256, 0, stream>>>(
      attn_o, wt_o, out);
}